// Round 1
// baseline (12209.762 us; speedup 1.0000x reference)
//
#include <hip/hip_runtime.h>

// ---------------- sizes ----------------
// B=8, N=4096, S=1024, K=16, C1=64, D=512, C2=128
// positions P = 8*1024*16 = 131072
#define EPSBN 1e-5f

// ---------------- ws byte offsets ----------------
#define WS_FPS_IDX   0u           // 8*1024*4          = 32768
#define WS_KNN_IDX   32768u       // 131072*4          = 524288
#define WS_X1        1048576u     // 131072*64*4       = 33554432 (also holds x2 in-place)
#define WS_BNP1      34603008u    // 512*128*4         = 262144
#define WS_BN1S      34865152u    // 128*4             = 512
#define WS_BNP2      34865664u    // 1024*256*4        = 1048576
#define WS_BN2S      35914240u    // 256*4             = 1024
#define WS_FC1T      35915264u    // 64*512*4          = 131072
#define WS_WQT       36046336u    // 512*512*4         = 1048576
#define WS_WKT       37094912u
#define WS_WVT       38143488u
#define WS_FC2T      39192064u    // 512*64*4          = 131072  (end ~39.3MB)

// out[c2*R + r] = in[r*C + c2]
__global__ void transpose_kernel(const float* __restrict__ in, float* __restrict__ out,
                                 int R, int C) {
  int idx = blockIdx.x * blockDim.x + threadIdx.x;
  if (idx < R * C) {
    int r = idx / C;
    int c = idx - r * C;
    out[c * R + r] = in[idx];
  }
}

// ---------------- FPS: 8 blocks x 512 threads ----------------
__global__ __launch_bounds__(512) void fps_kernel(const float* __restrict__ xyz,
                                                  int* __restrict__ fps_idx,
                                                  float* __restrict__ out_xyz) {
  __shared__ float sx[4096], sy[4096], sz[4096];
  __shared__ float pv[8];
  __shared__ int   pi[8];
  __shared__ float bc[3];
  __shared__ int   bsel;
  const int b = blockIdx.x;
  const int t = threadIdx.x;
  const float* xb = xyz + (size_t)b * 4096 * 3;
  float px[8], py[8], pz[8], pd[8];
#pragma unroll
  for (int i = 0; i < 8; ++i) {
    int j = i * 512 + t;
    float x = xb[j * 3 + 0], y = xb[j * 3 + 1], z = xb[j * 3 + 2];
    px[i] = x; py[i] = y; pz[i] = z; pd[i] = 1e10f;
    sx[j] = x; sy[j] = y; sz[j] = z;
  }
  __syncthreads();
  int sel = 0;
  float cx = sx[0], cy = sy[0], cz = sz[0];
  const int lane = t & 63, wid = t >> 6;
  for (int it = 0; it < 1024; ++it) {
    if (t == 0) {
      fps_idx[b * 1024 + it] = sel;
      out_xyz[(size_t)(b * 1024 + it) * 3 + 0] = cx;
      out_xyz[(size_t)(b * 1024 + it) * 3 + 1] = cy;
      out_xyz[(size_t)(b * 1024 + it) * 3 + 2] = cz;
    }
    float bv = -1.0f; int bi = 0;
#pragma unroll
    for (int i = 0; i < 8; ++i) {
      int j = i * 512 + t;
      float dx = __fsub_rn(px[i], cx);
      float dy = __fsub_rn(py[i], cy);
      float dz = __fsub_rn(pz[i], cz);
      float d = __fadd_rn(__fadd_rn(__fmul_rn(dx, dx), __fmul_rn(dy, dy)), __fmul_rn(dz, dz));
      float nd = fminf(pd[i], d);
      pd[i] = nd;
      if (nd > bv) { bv = nd; bi = j; }  // ascending j -> first max kept
    }
#pragma unroll
    for (int off = 32; off > 0; off >>= 1) {
      float ov = __shfl_down(bv, off);
      int   oi = __shfl_down(bi, off);
      if (ov > bv || (ov == bv && oi < bi)) { bv = ov; bi = oi; }
    }
    if (lane == 0) { pv[wid] = bv; pi[wid] = bi; }
    __syncthreads();
    if (t == 0) {
      float v = pv[0]; int ix = pi[0];
#pragma unroll
      for (int w = 1; w < 8; ++w) {
        float ov = pv[w]; int oi = pi[w];
        if (ov > v || (ov == v && oi < ix)) { v = ov; ix = oi; }
      }
      bsel = ix; bc[0] = sx[ix]; bc[1] = sy[ix]; bc[2] = sz[ix];
    }
    __syncthreads();
    sel = bsel; cx = bc[0]; cy = bc[1]; cz = bc[2];
  }
}

// ---------------- kNN: 32 blocks x 256 threads ----------------
__global__ __launch_bounds__(256) void knn_kernel(const float* __restrict__ xyz,
                                                  const float* __restrict__ new_xyz,
                                                  int* __restrict__ knn_idx) {
  __shared__ float sx[4096], sy[4096], sz[4096], pp[4096];
  const int b = blockIdx.x >> 2;
  const int s = ((blockIdx.x & 3) << 8) + threadIdx.x;
  const float* xb = xyz + (size_t)b * 4096 * 3;
  for (int i = 0; i < 16; ++i) {
    int j = i * 256 + threadIdx.x;
    float x = xb[j * 3 + 0], y = xb[j * 3 + 1], z = xb[j * 3 + 2];
    sx[j] = x; sy[j] = y; sz[j] = z;
    pp[j] = __fadd_rn(__fadd_rn(__fmul_rn(x, x), __fmul_rn(y, y)), __fmul_rn(z, z));
  }
  __syncthreads();
  const size_t srow = (size_t)(b * 1024 + s);
  const float cx = new_xyz[srow * 3 + 0];
  const float cy = new_xyz[srow * 3 + 1];
  const float cz = new_xyz[srow * 3 + 2];
  const float cc = __fadd_rn(__fadd_rn(__fmul_rn(cx, cx), __fmul_rn(cy, cy)), __fmul_rn(cz, cz));
  float ld[16]; int li[16];
#pragma unroll
  for (int q = 0; q < 16; ++q) { ld[q] = 3.4e38f; li[q] = 0; }
  for (int j = 0; j < 4096; ++j) {
    float dot = __fadd_rn(__fadd_rn(__fmul_rn(cx, sx[j]), __fmul_rn(cy, sy[j])), __fmul_rn(cz, sz[j]));
    float d = __fsub_rn(__fadd_rn(cc, pp[j]), __fmul_rn(2.0f, dot));
    if (d < ld[15]) {
      float cd = d; int ci = j;
#pragma unroll
      for (int q = 0; q < 16; ++q) {
        bool sw = (cd < ld[q]) || (cd == ld[q] && ci < li[q]);
        float td = ld[q]; int ti = li[q];
        if (sw) { ld[q] = cd; li[q] = ci; cd = td; ci = ti; }
      }
    }
  }
  int* op = knn_idx + srow * 16;
#pragma unroll
  for (int q = 0; q < 16; ++q) op[q] = li[q];
}

// ---------------- gather + mlp1: 512 blocks x 256 threads ----------------
__global__ __launch_bounds__(256) void mlp1_kernel(const float* __restrict__ feat,
                                                   const int* __restrict__ knn_idx,
                                                   const float* __restrict__ w1,
                                                   const float* __restrict__ b1,
                                                   float* __restrict__ x1) {
  __shared__ float w1s[64 * 64];
  __shared__ float b1s[64];
  const int t = threadIdx.x;
  for (int i = t; i < 4096; i += 256) w1s[i] = w1[i];
  if (t < 64) b1s[t] = b1[t];
  __syncthreads();
  const int pos = blockIdx.x * 256 + t;
  const int b = pos >> 14;
  const int n = knn_idx[pos];
  const float4* fp = reinterpret_cast<const float4*>(feat + ((size_t)(b * 4096 + n)) * 64);
  float4 fr[16];
#pragma unroll
  for (int i = 0; i < 16; ++i) fr[i] = fp[i];
  float4* op = reinterpret_cast<float4*>(x1 + (size_t)pos * 64);
#pragma unroll
  for (int cq = 0; cq < 16; ++cq) {
    float a0 = b1s[cq * 4 + 0], a1 = b1s[cq * 4 + 1], a2 = b1s[cq * 4 + 2], a3 = b1s[cq * 4 + 3];
#pragma unroll
    for (int iq = 0; iq < 16; ++iq) {
      float4 f4 = fr[iq];
      float4 wa = *reinterpret_cast<const float4*>(&w1s[(cq * 4 + 0) * 64 + iq * 4]);
      float4 wb = *reinterpret_cast<const float4*>(&w1s[(cq * 4 + 1) * 64 + iq * 4]);
      float4 wc = *reinterpret_cast<const float4*>(&w1s[(cq * 4 + 2) * 64 + iq * 4]);
      float4 wd = *reinterpret_cast<const float4*>(&w1s[(cq * 4 + 3) * 64 + iq * 4]);
      a0 += f4.x * wa.x + f4.y * wa.y + f4.z * wa.z + f4.w * wa.w;
      a1 += f4.x * wb.x + f4.y * wb.y + f4.z * wb.z + f4.w * wb.w;
      a2 += f4.x * wc.x + f4.y * wc.y + f4.z * wc.z + f4.w * wc.w;
      a3 += f4.x * wd.x + f4.y * wd.y + f4.z * wd.z + f4.w * wd.w;
    }
    op[cq] = make_float4(a0, a1, a2, a3);
  }
}

// ---------------- BN1 stats: 512 blocks x 256 ----------------
__global__ __launch_bounds__(256) void bn1_stats_kernel(const float* __restrict__ x1,
                                                        float* __restrict__ bnp1) {
  __shared__ float ls[4][64], lq[4][64];
  const int t = threadIdx.x, c = t & 63, g = t >> 6;
  const float* p = x1 + ((size_t)blockIdx.x * 256 + g * 64) * 64 + c;
  float s = 0.f, s2 = 0.f;
  for (int i = 0; i < 64; ++i) { float v = p[(size_t)i * 64]; s += v; s2 = fmaf(v, v, s2); }
  ls[g][c] = s; lq[g][c] = s2;
  __syncthreads();
  if (t < 64) {
    bnp1[blockIdx.x * 128 + t]      = ls[0][t] + ls[1][t] + ls[2][t] + ls[3][t];
    bnp1[blockIdx.x * 128 + 64 + t] = lq[0][t] + lq[1][t] + lq[2][t] + lq[3][t];
  }
}

__global__ void bn1_final_kernel(const float* __restrict__ bnp1, const float* __restrict__ g1,
                                 const float* __restrict__ bt1, float* __restrict__ bn1s) {
  int c = threadIdx.x;  // 64
  float S = 0.f, Q = 0.f;
  for (int i = 0; i < 512; ++i) { S += bnp1[i * 128 + c]; Q += bnp1[i * 128 + 64 + c]; }
  float m = S * (1.0f / 131072.0f);
  float var = Q * (1.0f / 131072.0f) - m * m;
  float sc = g1[c] * rsqrtf(var + EPSBN);
  bn1s[c] = sc;
  bn1s[64 + c] = bt1[c] - m * sc;
}

// ---------------- transformer: 8192 blocks x 512 threads ----------------
__global__ __launch_bounds__(512) void transformer_kernel(
    float* __restrict__ x1, const float* __restrict__ bn1s,
    const float* __restrict__ fc1T, const float* __restrict__ fc1b,
    const float* __restrict__ wqT, const float* __restrict__ wkT, const float* __restrict__ wvT,
    const float* __restrict__ fc2T, const float* __restrict__ fc2b) {
  __shared__ float xg[16][68];
  __shared__ float hs[16][516];
  __shared__ float qs[16][516];
  __shared__ float ks[16][516];
  __shared__ float sS[16][16];
  __shared__ float attnL[16][16];
  const int t = threadIdx.x;
  const size_t base = (size_t)blockIdx.x * 1024;  // 16*64 floats per group

  // A: load + BN1 + ReLU  (xg also serves as 'pre')
  {
    int o = t * 2;
    int k = o >> 6, c = o & 63;
    float2 v = *reinterpret_cast<const float2*>(x1 + base + o);
    float s0 = bn1s[c], h0 = bn1s[64 + c];
    float s1 = bn1s[c + 1], h1 = bn1s[64 + c + 1];
    xg[k][c]     = fmaxf(0.f, v.x * s0 + h0);
    xg[k][c + 1] = fmaxf(0.f, v.y * s1 + h1);
  }
  __syncthreads();

  // B: h = xg @ fc1^T + b   (thread t owns column c=t)
  {
    const int c = t;
    float acc[16];
#pragma unroll
    for (int r = 0; r < 16; ++r) acc[r] = 0.f;
    for (int j = 0; j < 64; j += 4) {
      float w0 = fc1T[(j + 0) * 512 + c];
      float w1v = fc1T[(j + 1) * 512 + c];
      float w2v = fc1T[(j + 2) * 512 + c];
      float w3v = fc1T[(j + 3) * 512 + c];
#pragma unroll
      for (int r = 0; r < 16; ++r) {
        float4 xv = *reinterpret_cast<const float4*>(&xg[r][j]);
        acc[r] += xv.x * w0 + xv.y * w1v + xv.z * w2v + xv.w * w3v;
      }
    }
    float bb = fc1b[c];
#pragma unroll
    for (int r = 0; r < 16; ++r) hs[r][c] = acc[r] + bb;
  }
  __syncthreads();

  // C: q = h@wq^T, k = h@wk^T (fused to reuse h reads)
  {
    const int c = t;
    float aq[16], ak[16];
#pragma unroll
    for (int r = 0; r < 16; ++r) { aq[r] = 0.f; ak[r] = 0.f; }
    for (int j = 0; j < 512; j += 4) {
      float q0 = wqT[(j + 0) * 512 + c], q1 = wqT[(j + 1) * 512 + c];
      float q2 = wqT[(j + 2) * 512 + c], q3 = wqT[(j + 3) * 512 + c];
      float k0 = wkT[(j + 0) * 512 + c], k1 = wkT[(j + 1) * 512 + c];
      float k2 = wkT[(j + 2) * 512 + c], k3 = wkT[(j + 3) * 512 + c];
#pragma unroll
      for (int r = 0; r < 16; ++r) {
        float4 hv = *reinterpret_cast<const float4*>(&hs[r][j]);
        aq[r] += hv.x * q0 + hv.y * q1 + hv.z * q2 + hv.w * q3;
        ak[r] += hv.x * k0 + hv.y * k1 + hv.z * k2 + hv.w * k3;
      }
    }
#pragma unroll
    for (int r = 0; r < 16; ++r) { qs[r][c] = aq[r]; ks[r][c] = ak[r]; }
  }
  __syncthreads();

  // D: S = q k^T / sqrt(512)
  if (t < 256) {
    const int n = t >> 4, m = t & 15;
    float acc = 0.f;
    for (int j = 0; j < 512; j += 4) {
      float4 qv = *reinterpret_cast<const float4*>(&qs[n][j]);
      float4 kv = *reinterpret_cast<const float4*>(&ks[m][j]);
      acc += qv.x * kv.x + qv.y * kv.y + qv.z * kv.z + qv.w * kv.w;
    }
    sS[n][m] = acc * 0.04419417382415922f;  // 1/sqrt(512)
  }
  __syncthreads();
  if (t < 16) {
    float mx = -3.4e38f;
#pragma unroll
    for (int m = 0; m < 16; ++m) mx = fmaxf(mx, sS[t][m]);
    float e[16]; float sum = 0.f;
#pragma unroll
    for (int m = 0; m < 16; ++m) { e[m] = expf(sS[t][m] - mx); sum += e[m]; }
#pragma unroll
    for (int m = 0; m < 16; ++m) attnL[t][m] = e[m] / sum;
  }
  __syncthreads();

  // E: ah = attn @ h  -> written back into hs (column-local, race-free)
  {
    const int c = t;
    float a[16];
#pragma unroll
    for (int r = 0; r < 16; ++r) a[r] = 0.f;
#pragma unroll
    for (int m = 0; m < 16; ++m) {
      float hv = hs[m][c];
#pragma unroll
      for (int r = 0; r < 16; ++r) a[r] = fmaf(attnL[r][m], hv, a[r]);
    }
#pragma unroll
    for (int r = 0; r < 16; ++r) hs[r][c] = a[r];
  }
  __syncthreads();

  // F: res = ah @ wv^T  -> into ks
  {
    const int c = t;
    float a[16];
#pragma unroll
    for (int r = 0; r < 16; ++r) a[r] = 0.f;
    for (int j = 0; j < 512; j += 4) {
      float v0 = wvT[(j + 0) * 512 + c], v1 = wvT[(j + 1) * 512 + c];
      float v2 = wvT[(j + 2) * 512 + c], v3 = wvT[(j + 3) * 512 + c];
#pragma unroll
      for (int r = 0; r < 16; ++r) {
        float4 av = *reinterpret_cast<const float4*>(&hs[r][j]);
        a[r] += av.x * v0 + av.y * v1 + av.z * v2 + av.w * v3;
      }
    }
#pragma unroll
    for (int r = 0; r < 16; ++r) ks[r][c] = a[r];
  }
  __syncthreads();

  // G: x2 = res @ fc2^T + fc2b + pre  (j-sliced partials into qs, then combine)
  {
    const int c = t & 63, sl = t >> 6;
    float a[16];
#pragma unroll
    for (int r = 0; r < 16; ++r) a[r] = 0.f;
    const int j0 = sl * 64;
    for (int j = j0; j < j0 + 64; j += 4) {
      float w0 = fc2T[(j + 0) * 64 + c], w1v = fc2T[(j + 1) * 64 + c];
      float w2v = fc2T[(j + 2) * 64 + c], w3v = fc2T[(j + 3) * 64 + c];
#pragma unroll
      for (int r = 0; r < 16; ++r) {
        float4 rv = *reinterpret_cast<const float4*>(&ks[r][j]);
        a[r] += rv.x * w0 + rv.y * w1v + rv.z * w2v + rv.w * w3v;
      }
    }
#pragma unroll
    for (int r = 0; r < 16; ++r) qs[r][sl * 64 + c] = a[r];
  }
  __syncthreads();
  {
#pragma unroll
    for (int h2 = 0; h2 < 2; ++h2) {
      int o = h2 * 512 + t;
      int r = o >> 6, c = o & 63;
      float sum = 0.f;
#pragma unroll
      for (int sl2 = 0; sl2 < 8; ++sl2) sum += qs[r][sl2 * 64 + c];
      sum += fc2b[c];
      sum += xg[r][c];
      x1[base + o] = sum;  // x2 in-place
    }
  }
}

// ---------------- BN2 stats (computes x3 on the fly): 1024 blocks x 256 ----------------
__global__ __launch_bounds__(256) void bn2_stats_kernel(const float* __restrict__ x2,
                                                        const float* __restrict__ w2,
                                                        const float* __restrict__ b2,
                                                        float* __restrict__ bnp2) {
  __shared__ float sx2[128 * 64];
  __shared__ float ps[2][128], pq[2][128];
  const int t = threadIdx.x;
  const float4* s4 = reinterpret_cast<const float4*>(x2 + (size_t)blockIdx.x * 128 * 64);
  float4* d4 = reinterpret_cast<float4*>(sx2);
  for (int i = 0; i < 8; ++i) d4[i * 256 + t] = s4[i * 256 + t];
  __syncthreads();
  const int c = t & 127, h = t >> 7;
  float4 wreg[16];
  const float4* w4 = reinterpret_cast<const float4*>(w2 + c * 64);
#pragma unroll
  for (int i = 0; i < 16; ++i) wreg[i] = w4[i];
  const float bb = b2[c];
  float s = 0.f, q = 0.f;
  for (int p = 0; p < 64; ++p) {
    const float4* xr = reinterpret_cast<const float4*>(&sx2[(h * 64 + p) * 64]);
    float acc = bb;
#pragma unroll
    for (int i = 0; i < 16; ++i) {
      float4 xv = xr[i];
      acc += xv.x * wreg[i].x + xv.y * wreg[i].y + xv.z * wreg[i].z + xv.w * wreg[i].w;
    }
    s += acc; q = fmaf(acc, acc, q);
  }
  ps[h][c] = s; pq[h][c] = q;
  __syncthreads();
  if (t < 128) {
    bnp2[blockIdx.x * 256 + t]       = ps[0][t] + ps[1][t];
    bnp2[blockIdx.x * 256 + 128 + t] = pq[0][t] + pq[1][t];
  }
}

__global__ void bn2_final_kernel(const float* __restrict__ bnp2, const float* __restrict__ g2,
                                 const float* __restrict__ bt2, float* __restrict__ bn2s) {
  int c = threadIdx.x;  // 128
  float S = 0.f, Q = 0.f;
  for (int i = 0; i < 1024; ++i) { S += bnp2[i * 256 + c]; Q += bnp2[i * 256 + 128 + c]; }
  float m = S * (1.0f / 131072.0f);
  float var = Q * (1.0f / 131072.0f) - m * m;
  float sc = g2[c] * rsqrtf(var + EPSBN);
  bn2s[c] = sc;
  bn2s[128 + c] = bt2[c] - m * sc;
}

// ---------------- final: mlp2 + BN2 + ReLU + maxpool: 8192 blocks x 128 ----------------
__global__ __launch_bounds__(128) void final_kernel(const float* __restrict__ x2,
                                                    const float* __restrict__ w2,
                                                    const float* __restrict__ b2,
                                                    const float* __restrict__ bn2s,
                                                    float* __restrict__ out) {
  __shared__ float sx2[16 * 64];
  const int t = threadIdx.x;
  const float4* s4 = reinterpret_cast<const float4*>(x2 + (size_t)blockIdx.x * 1024);
  float4* d4 = reinterpret_cast<float4*>(sx2);
  for (int i = 0; i < 2; ++i) d4[i * 128 + t] = s4[i * 128 + t];
  __syncthreads();
  const int c = t;
  float4 wreg[16];
  const float4* w4 = reinterpret_cast<const float4*>(w2 + c * 64);
#pragma unroll
  for (int i = 0; i < 16; ++i) wreg[i] = w4[i];
  const float bb = b2[c], sc = bn2s[c], sh = bn2s[128 + c];
  float mx = -3.4e38f;
  for (int k = 0; k < 16; ++k) {
    const float4* xr = reinterpret_cast<const float4*>(&sx2[k * 64]);
    float acc = bb;
#pragma unroll
    for (int i = 0; i < 16; ++i) {
      float4 xv = xr[i];
      acc += xv.x * wreg[i].x + xv.y * wreg[i].y + xv.z * wreg[i].z + xv.w * wreg[i].w;
    }
    float y = fmaxf(0.f, acc * sc + sh);
    mx = fmaxf(mx, y);
  }
  out[24576 + (size_t)blockIdx.x * 128 + c] = mx;
}

// ---------------- launch ----------------
extern "C" void kernel_launch(void* const* d_in, const int* in_sizes, int n_in,
                              void* d_out, int out_size, void* d_ws, size_t ws_size,
                              hipStream_t stream) {
  const float* xyz  = (const float*)d_in[0];
  const float* feat = (const float*)d_in[1];
  const float* w1   = (const float*)d_in[2];
  const float* b1   = (const float*)d_in[3];
  const float* g1   = (const float*)d_in[4];
  const float* bt1  = (const float*)d_in[5];
  const float* fc1w = (const float*)d_in[6];
  const float* fc1b = (const float*)d_in[7];
  const float* wq   = (const float*)d_in[8];
  const float* wk   = (const float*)d_in[9];
  const float* wv   = (const float*)d_in[10];
  const float* fc2w = (const float*)d_in[11];
  const float* fc2b = (const float*)d_in[12];
  const float* w2   = (const float*)d_in[13];
  const float* b2   = (const float*)d_in[14];
  const float* g2   = (const float*)d_in[15];
  const float* bt2  = (const float*)d_in[16];
  float* out = (float*)d_out;
  char* ws = (char*)d_ws;

  int*   fps_idx = (int*)(ws + WS_FPS_IDX);
  int*   knn_idx = (int*)(ws + WS_KNN_IDX);
  float* x1      = (float*)(ws + WS_X1);
  float* bnp1    = (float*)(ws + WS_BNP1);
  float* bn1s    = (float*)(ws + WS_BN1S);
  float* bnp2    = (float*)(ws + WS_BNP2);
  float* bn2s    = (float*)(ws + WS_BN2S);
  float* fc1T    = (float*)(ws + WS_FC1T);
  float* wqT     = (float*)(ws + WS_WQT);
  float* wkT     = (float*)(ws + WS_WKT);
  float* wvT     = (float*)(ws + WS_WVT);
  float* fc2T    = (float*)(ws + WS_FC2T);

  transpose_kernel<<<(512 * 64 + 255) / 256, 256, 0, stream>>>(fc1w, fc1T, 512, 64);
  transpose_kernel<<<(512 * 512 + 255) / 256, 256, 0, stream>>>(wq, wqT, 512, 512);
  transpose_kernel<<<(512 * 512 + 255) / 256, 256, 0, stream>>>(wk, wkT, 512, 512);
  transpose_kernel<<<(512 * 512 + 255) / 256, 256, 0, stream>>>(wv, wvT, 512, 512);
  transpose_kernel<<<(64 * 512 + 255) / 256, 256, 0, stream>>>(fc2w, fc2T, 64, 512);

  fps_kernel<<<8, 512, 0, stream>>>(xyz, fps_idx, out);
  knn_kernel<<<32, 256, 0, stream>>>(xyz, out, knn_idx);
  mlp1_kernel<<<512, 256, 0, stream>>>(feat, knn_idx, w1, b1, x1);
  bn1_stats_kernel<<<512, 256, 0, stream>>>(x1, bnp1);
  bn1_final_kernel<<<1, 64, 0, stream>>>(bnp1, g1, bt1, bn1s);
  transformer_kernel<<<8192, 512, 0, stream>>>(x1, bn1s, fc1T, fc1b, wqT, wkT, wvT, fc2T, fc2b);
  bn2_stats_kernel<<<1024, 256, 0, stream>>>(x1, w2, b2, bnp2);
  bn2_final_kernel<<<1, 128, 0, stream>>>(bnp2, g2, bt2, bn2s);
  final_kernel<<<8192, 128, 0, stream>>>(x1, w2, b2, bn2s, out);
}

// Round 2
// 7236.507 us; speedup vs baseline: 1.6872x; 1.6872x over previous
//
#include <hip/hip_runtime.h>

// ---------------- sizes ----------------
// B=8, N=4096, S=1024, K=16, C1=64, D=512, C2=128
// positions P = 8*1024*16 = 131072
#define EPSBN 1e-5f
#define INVSQ 0.04419417382415922f  // 1/sqrt(512)

// ---------------- ws byte offsets ----------------
#define WS_KNN_IDX   32768u       // 131072*4          = 524288
#define WS_X1        1048576u     // 131072*64*4       = 33554432 (also holds x2 in-place)
#define WS_BNP1      34603008u    // 512*128*4         = 262144
#define WS_BN1S      34865152u    // 128*4             = 512
#define WS_BNP2      34865664u    // 1024*256*4        = 1048576
#define WS_BN2S      35914240u    // 256*4             = 1024
#define WS_A         35915264u    // 512*64*4          = 131072
#define WS_B         36046336u    // 512*64*4
#define WS_QB        36177408u    // 512*4
#define WS_KB        36179456u    // 512*4
#define WS_WC        36181504u    // 64*512*4          = 131072
#define WS_G         36312576u    // 64*64*4           = 16384
#define WS_ZT        36328960u    // 64*64*4
#define WS_U         36345344u    // 64*4
#define WS_W         36345600u
#define WS_TB        36345856u
#define WS_CC        36346112u    // 4

// ---------------- weight combines ----------------
// A = wq @ fc1w (512x64), B = wk @ fc1w, qb = wq@fc1b, kb = wk@fc1b
__global__ __launch_bounds__(256) void prep_AB(const float* __restrict__ wq,
                                               const float* __restrict__ wk,
                                               const float* __restrict__ fc1w,
                                               const float* __restrict__ fc1b,
                                               float* __restrict__ A, float* __restrict__ B,
                                               float* __restrict__ qb, float* __restrict__ kb) {
  int id = blockIdx.x * 256 + threadIdx.x;           // 0..65535
  int which = id >> 15;
  int rem = id & 32767;
  int r = rem >> 6, i = rem & 63;
  const float* W = which ? wk : wq;
  float s = 0.f;
  for (int d = 0; d < 512; ++d) s = fmaf(W[r * 512 + d], fc1w[d * 64 + i], s);
  (which ? B : A)[r * 64 + i] = s;
  if (i == 0) {
    float sb = 0.f;
    for (int d = 0; d < 512; ++d) sb = fmaf(W[r * 512 + d], fc1b[d], sb);
    (which ? kb : qb)[r] = sb;
  }
}

// Wc = fc2w @ wv (64x512)
__global__ __launch_bounds__(256) void prep_Wc(const float* __restrict__ fc2w,
                                               const float* __restrict__ wv,
                                               float* __restrict__ Wc) {
  int id = blockIdx.x * 256 + threadIdx.x;           // 0..32767
  int c = id >> 9, d = id & 511;
  float s = 0.f;
  for (int e = 0; e < 512; ++e) s = fmaf(fc2w[c * 512 + e], wv[e * 512 + d], s);
  Wc[c * 512 + d] = s;
}

// G[i][j] = inv * sum_d A[d][i]*B[d][j]; u[i]=inv*A^T kb; w[j]=inv*B^T qb; cc=inv*qb.kb
__global__ __launch_bounds__(256) void prep_G(const float* __restrict__ A,
                                              const float* __restrict__ B,
                                              const float* __restrict__ qb,
                                              const float* __restrict__ kb,
                                              float* __restrict__ G, float* __restrict__ u,
                                              float* __restrict__ w, float* __restrict__ cc) {
  int id = blockIdx.x * 256 + threadIdx.x;
  if (id < 4096) {
    int i = id >> 6, j = id & 63;
    float s = 0.f;
    for (int d = 0; d < 512; ++d) s = fmaf(A[d * 64 + i], B[d * 64 + j], s);
    G[i * 64 + j] = s * INVSQ;
  } else if (id < 4160) {
    int i = id - 4096; float s = 0.f;
    for (int d = 0; d < 512; ++d) s = fmaf(A[d * 64 + i], kb[d], s);
    u[i] = s * INVSQ;
  } else if (id < 4224) {
    int j = id - 4160; float s = 0.f;
    for (int d = 0; d < 512; ++d) s = fmaf(B[d * 64 + j], qb[d], s);
    w[j] = s * INVSQ;
  } else if (id == 4224) {
    float s = 0.f;
    for (int d = 0; d < 512; ++d) s = fmaf(qb[d], kb[d], s);
    cc[0] = s * INVSQ;
  }
}

// ZT[i][c] = sum_d Wc[c][d]*fc1w[d][i];  tb[c] = fc2b[c] + Wc[c]·fc1b
__global__ __launch_bounds__(256) void prep_Z(const float* __restrict__ Wc,
                                              const float* __restrict__ fc1w,
                                              const float* __restrict__ fc1b,
                                              const float* __restrict__ fc2b,
                                              float* __restrict__ ZT, float* __restrict__ tb) {
  int id = blockIdx.x * 256 + threadIdx.x;
  if (id < 4096) {
    int i = id >> 6, c = id & 63;
    float s = 0.f;
    for (int d = 0; d < 512; ++d) s = fmaf(Wc[c * 512 + d], fc1w[d * 64 + i], s);
    ZT[i * 64 + c] = s;
  } else if (id < 4160) {
    int c = id - 4096; float s = 0.f;
    for (int d = 0; d < 512; ++d) s = fmaf(Wc[c * 512 + d], fc1b[d], s);
    tb[c] = s + fc2b[c];
  }
}

// ---------------- FPS: 8 blocks x 64 threads (one wave, no barriers) ----------------
__global__ __launch_bounds__(64) void fps_kernel(const float* __restrict__ xyz,
                                                 float* __restrict__ out_xyz) {
  __shared__ float4 spts[4096];
  const int b = blockIdx.x;
  const int t = threadIdx.x;
  const float* xb = xyz + (size_t)b * 4096 * 3;
  for (int i = 0; i < 64; ++i) {
    int j = i * 64 + t;
    spts[j] = make_float4(xb[j * 3 + 0], xb[j * 3 + 1], xb[j * 3 + 2], 0.f);
  }
  float pd[64];
#pragma unroll
  for (int i = 0; i < 64; ++i) pd[i] = 1e10f;
  __syncthreads();
  float4 c4 = spts[0];
  for (int it = 0; it < 1024; ++it) {
    if (t == 0) {
      out_xyz[(size_t)(b * 1024 + it) * 3 + 0] = c4.x;
      out_xyz[(size_t)(b * 1024 + it) * 3 + 1] = c4.y;
      out_xyz[(size_t)(b * 1024 + it) * 3 + 2] = c4.z;
    }
    float bv = -1.0f; int bi = 0;
#pragma unroll
    for (int i = 0; i < 64; ++i) {
      float4 p = spts[i * 64 + t];
      float dx = __fsub_rn(p.x, c4.x);
      float dy = __fsub_rn(p.y, c4.y);
      float dz = __fsub_rn(p.z, c4.z);
      float d = __fadd_rn(__fadd_rn(__fmul_rn(dx, dx), __fmul_rn(dy, dy)), __fmul_rn(dz, dz));
      float nd = fminf(pd[i], d);
      pd[i] = nd;
      if (nd > bv) { bv = nd; bi = i * 64 + t; }  // ascending index -> first max kept
    }
#pragma unroll
    for (int off = 1; off < 64; off <<= 1) {
      float ov = __shfl_xor(bv, off);
      int   oi = __shfl_xor(bi, off);
      if (ov > bv || (ov == bv && oi < bi)) { bv = ov; bi = oi; }
    }
    c4 = spts[bi];  // uniform index -> broadcast
  }
}

// ---------------- kNN: 32 blocks x 256 threads ----------------
__global__ __launch_bounds__(256) void knn_kernel(const float* __restrict__ xyz,
                                                  const float* __restrict__ new_xyz,
                                                  int* __restrict__ knn_idx) {
  __shared__ float sx[4096], sy[4096], sz[4096], pp[4096];
  const int b = blockIdx.x >> 2;
  const int s = ((blockIdx.x & 3) << 8) + threadIdx.x;
  const float* xb = xyz + (size_t)b * 4096 * 3;
  for (int i = 0; i < 16; ++i) {
    int j = i * 256 + threadIdx.x;
    float x = xb[j * 3 + 0], y = xb[j * 3 + 1], z = xb[j * 3 + 2];
    sx[j] = x; sy[j] = y; sz[j] = z;
    pp[j] = __fadd_rn(__fadd_rn(__fmul_rn(x, x), __fmul_rn(y, y)), __fmul_rn(z, z));
  }
  __syncthreads();
  const size_t srow = (size_t)(b * 1024 + s);
  const float cx = new_xyz[srow * 3 + 0];
  const float cy = new_xyz[srow * 3 + 1];
  const float cz = new_xyz[srow * 3 + 2];
  const float cc = __fadd_rn(__fadd_rn(__fmul_rn(cx, cx), __fmul_rn(cy, cy)), __fmul_rn(cz, cz));
  float ld[16]; int li[16];
#pragma unroll
  for (int q = 0; q < 16; ++q) { ld[q] = 3.4e38f; li[q] = 0; }
  for (int j = 0; j < 4096; ++j) {
    float dot = __fadd_rn(__fadd_rn(__fmul_rn(cx, sx[j]), __fmul_rn(cy, sy[j])), __fmul_rn(cz, sz[j]));
    float d = __fsub_rn(__fadd_rn(cc, pp[j]), __fmul_rn(2.0f, dot));
    if (d < ld[15]) {
      float cd = d; int ci = j;
#pragma unroll
      for (int q = 0; q < 16; ++q) {
        bool sw = (cd < ld[q]) || (cd == ld[q] && ci < li[q]);
        float td = ld[q]; int ti = li[q];
        if (sw) { ld[q] = cd; li[q] = ci; cd = td; ci = ti; }
      }
    }
  }
  int* op = knn_idx + srow * 16;
#pragma unroll
  for (int q = 0; q < 16; ++q) op[q] = li[q];
}

// ---------------- gather + mlp1: 512 blocks x 256 threads ----------------
__global__ __launch_bounds__(256) void mlp1_kernel(const float* __restrict__ feat,
                                                   const int* __restrict__ knn_idx,
                                                   const float* __restrict__ w1,
                                                   const float* __restrict__ b1,
                                                   float* __restrict__ x1) {
  __shared__ float w1s[64 * 64];
  __shared__ float b1s[64];
  const int t = threadIdx.x;
  for (int i = t; i < 4096; i += 256) w1s[i] = w1[i];
  if (t < 64) b1s[t] = b1[t];
  __syncthreads();
  const int pos = blockIdx.x * 256 + t;
  const int b = pos >> 14;
  const int n = knn_idx[pos];
  const float4* fp = reinterpret_cast<const float4*>(feat + ((size_t)(b * 4096 + n)) * 64);
  float4 fr[16];
#pragma unroll
  for (int i = 0; i < 16; ++i) fr[i] = fp[i];
  float4* op = reinterpret_cast<float4*>(x1 + (size_t)pos * 64);
#pragma unroll
  for (int cq = 0; cq < 16; ++cq) {
    float a0 = b1s[cq * 4 + 0], a1 = b1s[cq * 4 + 1], a2 = b1s[cq * 4 + 2], a3 = b1s[cq * 4 + 3];
#pragma unroll
    for (int iq = 0; iq < 16; ++iq) {
      float4 f4 = fr[iq];
      float4 wa = *reinterpret_cast<const float4*>(&w1s[(cq * 4 + 0) * 64 + iq * 4]);
      float4 wb = *reinterpret_cast<const float4*>(&w1s[(cq * 4 + 1) * 64 + iq * 4]);
      float4 wc = *reinterpret_cast<const float4*>(&w1s[(cq * 4 + 2) * 64 + iq * 4]);
      float4 wd = *reinterpret_cast<const float4*>(&w1s[(cq * 4 + 3) * 64 + iq * 4]);
      a0 += f4.x * wa.x + f4.y * wa.y + f4.z * wa.z + f4.w * wa.w;
      a1 += f4.x * wb.x + f4.y * wb.y + f4.z * wb.z + f4.w * wb.w;
      a2 += f4.x * wc.x + f4.y * wc.y + f4.z * wc.z + f4.w * wc.w;
      a3 += f4.x * wd.x + f4.y * wd.y + f4.z * wd.z + f4.w * wd.w;
    }
    op[cq] = make_float4(a0, a1, a2, a3);
  }
}

// ---------------- BN1 stats: 512 blocks x 256 ----------------
__global__ __launch_bounds__(256) void bn1_stats_kernel(const float* __restrict__ x1,
                                                        float* __restrict__ bnp1) {
  __shared__ float ls[4][64], lq[4][64];
  const int t = threadIdx.x, c = t & 63, g = t >> 6;
  const float* p = x1 + ((size_t)blockIdx.x * 256 + g * 64) * 64 + c;
  float s = 0.f, s2 = 0.f;
  for (int i = 0; i < 64; ++i) { float v = p[(size_t)i * 64]; s += v; s2 = fmaf(v, v, s2); }
  ls[g][c] = s; lq[g][c] = s2;
  __syncthreads();
  if (t < 64) {
    bnp1[blockIdx.x * 128 + t]      = ls[0][t] + ls[1][t] + ls[2][t] + ls[3][t];
    bnp1[blockIdx.x * 128 + 64 + t] = lq[0][t] + lq[1][t] + lq[2][t] + lq[3][t];
  }
}

__global__ void bn1_final_kernel(const float* __restrict__ bnp1, const float* __restrict__ g1,
                                 const float* __restrict__ bt1, float* __restrict__ bn1s) {
  int c = threadIdx.x;  // 64
  float S = 0.f, Q = 0.f;
  for (int i = 0; i < 512; ++i) { S += bnp1[i * 128 + c]; Q += bnp1[i * 128 + 64 + c]; }
  float m = S * (1.0f / 131072.0f);
  float var = Q * (1.0f / 131072.0f) - m * m;
  float sc = g1[c] * rsqrtf(var + EPSBN);
  bn1s[c] = sc;
  bn1s[64 + c] = bt1[c] - m * sc;
}

// ---------------- fused transformer (rank-64 collapsed): 8192 blocks x 64 ----------------
__global__ __launch_bounds__(64) void transformer_fused(
    float* __restrict__ x1, const float* __restrict__ bn1s,
    const float* __restrict__ G, const float* __restrict__ u, const float* __restrict__ w,
    const float* __restrict__ cc, const float* __restrict__ ZT, const float* __restrict__ tb) {
  __shared__ float pre[16][65];
  __shared__ float ts[16][65];
  __shared__ float ys[16][65];
  __shared__ float ss[16][17];
  __shared__ float spu[16], spw[16];
  const int c = threadIdx.x;
  const size_t base = (size_t)blockIdx.x * 1024;
  const float sc = bn1s[c], sh = bn1s[64 + c];
  float pc[16];
#pragma unroll
  for (int k = 0; k < 16; ++k) {
    float v = x1[base + k * 64 + c];
    float p = fmaxf(0.f, v * sc + sh);
    pc[k] = p; pre[k][c] = p;
  }
  __syncthreads();
  // t = pre@G (col c), y = pre@Z^T (col c)
  float tcol[16], ycol[16];
#pragma unroll
  for (int k = 0; k < 16; ++k) { tcol[k] = 0.f; ycol[k] = 0.f; }
  for (int i = 0; i < 64; ++i) {
    float g = G[i * 64 + c];
    float z = ZT[i * 64 + c];
#pragma unroll
    for (int k = 0; k < 16; ++k) {
      float p = pre[k][i];
      tcol[k] = fmaf(p, g, tcol[k]);
      ycol[k] = fmaf(p, z, ycol[k]);
    }
  }
#pragma unroll
  for (int k = 0; k < 16; ++k) { ts[k][c] = tcol[k]; ys[k][c] = ycol[k]; }
  if (c < 16) {
    float s = 0.f;
    for (int i = 0; i < 64; ++i) s = fmaf(pre[c][i], u[i], s);
    spu[c] = s;
  } else if (c < 32) {
    int m = c - 16; float s = 0.f;
    for (int i = 0; i < 64; ++i) s = fmaf(pre[m][i], w[i], s);
    spw[m] = s;
  }
  __syncthreads();
  // scores s[n][m] = t_n · pre_m + pu[n] + pw[m] + cc
  {
    const float cval = cc[0];
    const int m = c & 15, nb = c >> 4;
#pragma unroll
    for (int ng = 0; ng < 4; ++ng) {
      int n = ng * 4 + nb;
      float s = 0.f;
      for (int i = 0; i < 64; ++i) s = fmaf(ts[n][i], pre[m][i], s);
      ss[n][m] = s + spu[n] + spw[m] + cval;
    }
  }
  __syncthreads();
  if (c < 16) {
    float mx = -3.4e38f;
#pragma unroll
    for (int m = 0; m < 16; ++m) mx = fmaxf(mx, ss[c][m]);
    float e[16], sum = 0.f;
#pragma unroll
    for (int m = 0; m < 16; ++m) { e[m] = expf(ss[c][m] - mx); sum += e[m]; }
    float r = 1.0f / sum;
#pragma unroll
    for (int m = 0; m < 16; ++m) ss[c][m] = e[m] * r;
  }
  __syncthreads();
  const float tbc = tb[c];
  float o[16];
#pragma unroll
  for (int k = 0; k < 16; ++k) o[k] = 0.f;
#pragma unroll
  for (int m = 0; m < 16; ++m) {
    float yv = ys[m][c];
#pragma unroll
    for (int k = 0; k < 16; ++k) o[k] = fmaf(ss[k][m], yv, o[k]);
  }
#pragma unroll
  for (int k = 0; k < 16; ++k) x1[base + k * 64 + c] = o[k] + tbc + pc[k];
}

// ---------------- BN2 stats (computes mlp2 on the fly): 1024 blocks x 256 ----------------
__global__ __launch_bounds__(256) void bn2_stats_kernel(const float* __restrict__ x2,
                                                        const float* __restrict__ w2,
                                                        const float* __restrict__ b2,
                                                        float* __restrict__ bnp2) {
  __shared__ float sx2[128 * 64];
  __shared__ float ps[2][128], pq[2][128];
  const int t = threadIdx.x;
  const float4* s4 = reinterpret_cast<const float4*>(x2 + (size_t)blockIdx.x * 128 * 64);
  float4* d4 = reinterpret_cast<float4*>(sx2);
  for (int i = 0; i < 8; ++i) d4[i * 256 + t] = s4[i * 256 + t];
  __syncthreads();
  const int c = t & 127, h = t >> 7;
  float4 wreg[16];
  const float4* w4 = reinterpret_cast<const float4*>(w2 + c * 64);
#pragma unroll
  for (int i = 0; i < 16; ++i) wreg[i] = w4[i];
  const float bb = b2[c];
  float s = 0.f, q = 0.f;
  for (int p = 0; p < 64; ++p) {
    const float4* xr = reinterpret_cast<const float4*>(&sx2[(h * 64 + p) * 64]);
    float acc = bb;
#pragma unroll
    for (int i = 0; i < 16; ++i) {
      float4 xv = xr[i];
      acc += xv.x * wreg[i].x + xv.y * wreg[i].y + xv.z * wreg[i].z + xv.w * wreg[i].w;
    }
    s += acc; q = fmaf(acc, acc, q);
  }
  ps[h][c] = s; pq[h][c] = q;
  __syncthreads();
  if (t < 128) {
    bnp2[blockIdx.x * 256 + t]       = ps[0][t] + ps[1][t];
    bnp2[blockIdx.x * 256 + 128 + t] = pq[0][t] + pq[1][t];
  }
}

__global__ void bn2_final_kernel(const float* __restrict__ bnp2, const float* __restrict__ g2,
                                 const float* __restrict__ bt2, float* __restrict__ bn2s) {
  int c = threadIdx.x;  // 128
  float S = 0.f, Q = 0.f;
  for (int i = 0; i < 1024; ++i) { S += bnp2[i * 256 + c]; Q += bnp2[i * 256 + 128 + c]; }
  float m = S * (1.0f / 131072.0f);
  float var = Q * (1.0f / 131072.0f) - m * m;
  float sc = g2[c] * rsqrtf(var + EPSBN);
  bn2s[c] = sc;
  bn2s[128 + c] = bt2[c] - m * sc;
}

// ---------------- final: mlp2 + BN2 + ReLU + maxpool: 8192 blocks x 128 ----------------
__global__ __launch_bounds__(128) void final_kernel(const float* __restrict__ x2,
                                                    const float* __restrict__ w2,
                                                    const float* __restrict__ b2,
                                                    const float* __restrict__ bn2s,
                                                    float* __restrict__ out) {
  __shared__ float sx2[16 * 64];
  const int t = threadIdx.x;
  const float4* s4 = reinterpret_cast<const float4*>(x2 + (size_t)blockIdx.x * 1024);
  float4* d4 = reinterpret_cast<float4*>(sx2);
  for (int i = 0; i < 2; ++i) d4[i * 128 + t] = s4[i * 128 + t];
  __syncthreads();
  const int c = t;
  float4 wreg[16];
  const float4* w4 = reinterpret_cast<const float4*>(w2 + c * 64);
#pragma unroll
  for (int i = 0; i < 16; ++i) wreg[i] = w4[i];
  const float bb = b2[c], sc = bn2s[c], sh = bn2s[128 + c];
  float mx = -3.4e38f;
  for (int k = 0; k < 16; ++k) {
    const float4* xr = reinterpret_cast<const float4*>(&sx2[k * 64]);
    float acc = bb;
#pragma unroll
    for (int i = 0; i < 16; ++i) {
      float4 xv = xr[i];
      acc += xv.x * wreg[i].x + xv.y * wreg[i].y + xv.z * wreg[i].z + xv.w * wreg[i].w;
    }
    float y = fmaxf(0.f, acc * sc + sh);
    mx = fmaxf(mx, y);
  }
  out[24576 + (size_t)blockIdx.x * 128 + c] = mx;
}

// ---------------- launch ----------------
extern "C" void kernel_launch(void* const* d_in, const int* in_sizes, int n_in,
                              void* d_out, int out_size, void* d_ws, size_t ws_size,
                              hipStream_t stream) {
  const float* xyz  = (const float*)d_in[0];
  const float* feat = (const float*)d_in[1];
  const float* w1   = (const float*)d_in[2];
  const float* b1   = (const float*)d_in[3];
  const float* g1   = (const float*)d_in[4];
  const float* bt1  = (const float*)d_in[5];
  const float* fc1w = (const float*)d_in[6];
  const float* fc1b = (const float*)d_in[7];
  const float* wq   = (const float*)d_in[8];
  const float* wk   = (const float*)d_in[9];
  const float* wv   = (const float*)d_in[10];
  const float* fc2w = (const float*)d_in[11];
  const float* fc2b = (const float*)d_in[12];
  const float* w2   = (const float*)d_in[13];
  const float* b2   = (const float*)d_in[14];
  const float* g2   = (const float*)d_in[15];
  const float* bt2  = (const float*)d_in[16];
  float* out = (float*)d_out;
  char* ws = (char*)d_ws;

  int*   knn_idx = (int*)(ws + WS_KNN_IDX);
  float* x1      = (float*)(ws + WS_X1);
  float* bnp1    = (float*)(ws + WS_BNP1);
  float* bn1s    = (float*)(ws + WS_BN1S);
  float* bnp2    = (float*)(ws + WS_BNP2);
  float* bn2s    = (float*)(ws + WS_BN2S);
  float* Abuf    = (float*)(ws + WS_A);
  float* Bbuf    = (float*)(ws + WS_B);
  float* qb      = (float*)(ws + WS_QB);
  float* kb      = (float*)(ws + WS_KB);
  float* Wc      = (float*)(ws + WS_WC);
  float* G       = (float*)(ws + WS_G);
  float* ZT      = (float*)(ws + WS_ZT);
  float* u       = (float*)(ws + WS_U);
  float* w       = (float*)(ws + WS_W);
  float* tb      = (float*)(ws + WS_TB);
  float* cc      = (float*)(ws + WS_CC);

  prep_AB<<<256, 256, 0, stream>>>(wq, wk, fc1w, fc1b, Abuf, Bbuf, qb, kb);
  prep_Wc<<<128, 256, 0, stream>>>(fc2w, wv, Wc);
  prep_G<<<17, 256, 0, stream>>>(Abuf, Bbuf, qb, kb, G, u, w, cc);
  prep_Z<<<17, 256, 0, stream>>>(Wc, fc1w, fc1b, fc2b, ZT, tb);

  fps_kernel<<<8, 64, 0, stream>>>(xyz, out);
  knn_kernel<<<32, 256, 0, stream>>>(xyz, out, knn_idx);
  mlp1_kernel<<<512, 256, 0, stream>>>(feat, knn_idx, w1, b1, x1);
  bn1_stats_kernel<<<512, 256, 0, stream>>>(x1, bnp1);
  bn1_final_kernel<<<1, 64, 0, stream>>>(bnp1, g1, bt1, bn1s);
  transformer_fused<<<8192, 64, 0, stream>>>(x1, bn1s, G, u, w, cc, ZT, tb);
  bn2_stats_kernel<<<1024, 256, 0, stream>>>(x1, w2, b2, bnp2);
  bn2_final_kernel<<<1, 128, 0, stream>>>(bnp2, g2, bt2, bn2s);
  final_kernel<<<8192, 128, 0, stream>>>(x1, w2, b2, bn2s, out);
}

// Round 3
// 2725.422 us; speedup vs baseline: 4.4800x; 2.6552x over previous
//
#include <hip/hip_runtime.h>

// ---------------- sizes ----------------
// B=8, N=4096, S=1024, K=16, C1=64, D=512, C2=128
// positions P = 8*1024*16 = 131072
#define EPSBN 1e-5f
#define INVSQ 0.04419417382415922f  // 1/sqrt(512)

// ---------------- ws byte offsets ----------------
#define WS_KNN_IDX   32768u       // 131072*4          = 524288
#define WS_X1        1048576u     // 131072*64*4       = 33554432 (also holds x2 in-place)
#define WS_BNP1      34603008u    // 512*128*4         = 262144
#define WS_BN1S      34865152u    // 128*4             = 512
#define WS_BNP2      34865664u    // 1024*256*4        = 1048576
#define WS_BN2S      35914240u    // 256*4             = 1024
#define WS_A         35915264u    // 512*64*4          = 131072
#define WS_B         36046336u    // 512*64*4
#define WS_QB        36177408u    // 512*4
#define WS_KB        36179456u    // 512*4
#define WS_WC        36181504u    // 64*512*4          = 131072
#define WS_G         36312576u    // 64*64*4           = 16384
#define WS_ZT        36328960u    // 64*64*4
#define WS_U         36345344u    // 64*4
#define WS_W         36345600u
#define WS_TB        36345856u
#define WS_CC        36346112u    // 4
#define WS_PTS4      36346368u    // 32768*16          = 524288 (end ~36.9MB)

// ---------------- weight combines ----------------
__global__ __launch_bounds__(256) void prep_AB(const float* __restrict__ wq,
                                               const float* __restrict__ wk,
                                               const float* __restrict__ fc1w,
                                               const float* __restrict__ fc1b,
                                               float* __restrict__ A, float* __restrict__ B,
                                               float* __restrict__ qb, float* __restrict__ kb) {
  int id = blockIdx.x * 256 + threadIdx.x;           // 0..65535
  int which = id >> 15;
  int rem = id & 32767;
  int r = rem >> 6, i = rem & 63;
  const float* W = which ? wk : wq;
  float s = 0.f;
  for (int d = 0; d < 512; ++d) s = fmaf(W[r * 512 + d], fc1w[d * 64 + i], s);
  (which ? B : A)[r * 64 + i] = s;
  if (i == 0) {
    float sb = 0.f;
    for (int d = 0; d < 512; ++d) sb = fmaf(W[r * 512 + d], fc1b[d], sb);
    (which ? kb : qb)[r] = sb;
  }
}

__global__ __launch_bounds__(256) void prep_Wc(const float* __restrict__ fc2w,
                                               const float* __restrict__ wv,
                                               float* __restrict__ Wc) {
  int id = blockIdx.x * 256 + threadIdx.x;           // 0..32767
  int c = id >> 9, d = id & 511;
  float s = 0.f;
  for (int e = 0; e < 512; ++e) s = fmaf(fc2w[c * 512 + e], wv[e * 512 + d], s);
  Wc[c * 512 + d] = s;
}

__global__ __launch_bounds__(256) void prep_G(const float* __restrict__ A,
                                              const float* __restrict__ B,
                                              const float* __restrict__ qb,
                                              const float* __restrict__ kb,
                                              float* __restrict__ G, float* __restrict__ u,
                                              float* __restrict__ w, float* __restrict__ cc) {
  int id = blockIdx.x * 256 + threadIdx.x;
  if (id < 4096) {
    int i = id >> 6, j = id & 63;
    float s = 0.f;
    for (int d = 0; d < 512; ++d) s = fmaf(A[d * 64 + i], B[d * 64 + j], s);
    G[i * 64 + j] = s * INVSQ;
  } else if (id < 4160) {
    int i = id - 4096; float s = 0.f;
    for (int d = 0; d < 512; ++d) s = fmaf(A[d * 64 + i], kb[d], s);
    u[i] = s * INVSQ;
  } else if (id < 4224) {
    int j = id - 4160; float s = 0.f;
    for (int d = 0; d < 512; ++d) s = fmaf(B[d * 64 + j], qb[d], s);
    w[j] = s * INVSQ;
  } else if (id == 4224) {
    float s = 0.f;
    for (int d = 0; d < 512; ++d) s = fmaf(qb[d], kb[d], s);
    cc[0] = s * INVSQ;
  }
}

__global__ __launch_bounds__(256) void prep_Z(const float* __restrict__ Wc,
                                              const float* __restrict__ fc1w,
                                              const float* __restrict__ fc1b,
                                              const float* __restrict__ fc2b,
                                              float* __restrict__ ZT, float* __restrict__ tb) {
  int id = blockIdx.x * 256 + threadIdx.x;
  if (id < 4096) {
    int i = id >> 6, c = id & 63;
    float s = 0.f;
    for (int d = 0; d < 512; ++d) s = fmaf(Wc[c * 512 + d], fc1w[d * 64 + i], s);
    ZT[i * 64 + c] = s;
  } else if (id < 4160) {
    int c = id - 4096; float s = 0.f;
    for (int d = 0; d < 512; ++d) s = fmaf(Wc[c * 512 + d], fc1b[d], s);
    tb[c] = s + fc2b[c];
  }
}

// pack (x,y,z,|p|^2): 128 blocks x 256
__global__ __launch_bounds__(256) void pack_pts_kernel(const float* __restrict__ xyz,
                                                       float4* __restrict__ pts4) {
  int id = blockIdx.x * 256 + threadIdx.x;  // 0..32767
  float x = xyz[id * 3 + 0], y = xyz[id * 3 + 1], z = xyz[id * 3 + 2];
  float pp = __fadd_rn(__fadd_rn(__fmul_rn(x, x), __fmul_rn(y, y)), __fmul_rn(z, z));
  pts4[id] = make_float4(x, y, z, pp);
}

// ---------------- FPS: 8 blocks x 512 threads, points in registers ----------------
__global__ __launch_bounds__(512) void fps_kernel(const float* __restrict__ xyz,
                                                  float* __restrict__ out_xyz) {
  __shared__ float red[2][8][8];  // [buf][wave][v, j, x, y, z]
  __shared__ float initc[3];
  const int b = blockIdx.x;
  const int t = threadIdx.x;
  const int lane = t & 63, wid = t >> 6;
  const float* xb = xyz + (size_t)b * 4096 * 3;
  float px[8], py[8], pz[8], pd[8];
#pragma unroll
  for (int i = 0; i < 8; ++i) {
    int j = i * 512 + t;
    px[i] = xb[j * 3 + 0]; py[i] = xb[j * 3 + 1]; pz[i] = xb[j * 3 + 2];
    pd[i] = 1e10f;
  }
  if (t == 0) { initc[0] = px[0]; initc[1] = py[0]; initc[2] = pz[0]; }
  __syncthreads();
  float cx = initc[0], cy = initc[1], cz = initc[2];
  for (int it = 0; it < 1024; ++it) {
    if (t == 0) {
      out_xyz[(size_t)(b * 1024 + it) * 3 + 0] = cx;
      out_xyz[(size_t)(b * 1024 + it) * 3 + 1] = cy;
      out_xyz[(size_t)(b * 1024 + it) * 3 + 2] = cz;
    }
    float bv = -1.0f, bx = 0.f, by = 0.f, bz = 0.f; int bi = 0;
#pragma unroll
    for (int i = 0; i < 8; ++i) {
      float dx = __fsub_rn(px[i], cx);
      float dy = __fsub_rn(py[i], cy);
      float dz = __fsub_rn(pz[i], cz);
      float d = __fadd_rn(__fadd_rn(__fmul_rn(dx, dx), __fmul_rn(dy, dy)), __fmul_rn(dz, dz));
      float nd = fminf(pd[i], d);
      pd[i] = nd;
      bool g = nd > bv;  // ascending j within lane -> strict keeps first
      bv = g ? nd : bv; bi = g ? (i * 512 + t) : bi;
      bx = g ? px[i] : bx; by = g ? py[i] : by; bz = g ? pz[i] : bz;
    }
#pragma unroll
    for (int off = 1; off < 64; off <<= 1) {
      float ov = __shfl_xor(bv, off);
      int   oi = __shfl_xor(bi, off);
      float ox = __shfl_xor(bx, off);
      float oy = __shfl_xor(by, off);
      float oz = __shfl_xor(bz, off);
      bool tk = (ov > bv) || (ov == bv && oi < bi);
      bv = tk ? ov : bv; bi = tk ? oi : bi;
      bx = tk ? ox : bx; by = tk ? oy : by; bz = tk ? oz : bz;
    }
    const int p = it & 1;
    if (lane == 0) {
      red[p][wid][0] = bv; red[p][wid][1] = __int_as_float(bi);
      red[p][wid][2] = bx; red[p][wid][3] = by; red[p][wid][4] = bz;
    }
    __syncthreads();
    float v = red[p][0][0]; int ji = __float_as_int(red[p][0][1]);
    float nx = red[p][0][2], ny = red[p][0][3], nz = red[p][0][4];
#pragma unroll
    for (int w = 1; w < 8; ++w) {
      float ov = red[p][w][0]; int oi = __float_as_int(red[p][w][1]);
      bool tk = (ov > v) || (ov == v && oi < ji);
      v = tk ? ov : v; ji = tk ? oi : ji;
      nx = tk ? red[p][w][2] : nx; ny = tk ? red[p][w][3] : ny; nz = tk ? red[p][w][4] : nz;
    }
    cx = nx; cy = ny; cz = nz;
  }
}

// ---------------- kNN: one wave per center, 2048 blocks x 256, no LDS ----------------
__global__ __launch_bounds__(256) void knn_kernel(const float4* __restrict__ pts4,
                                                  const float* __restrict__ new_xyz,
                                                  int* __restrict__ knn_idx) {
  const int t = threadIdx.x & 63;
  const int wave = (blockIdx.x << 2) | (threadIdx.x >> 6);  // center id 0..8191
  const int b = wave >> 10;
  const float4* P = pts4 + (size_t)b * 4096;
  const float cx = new_xyz[(size_t)wave * 3 + 0];
  const float cy = new_xyz[(size_t)wave * 3 + 1];
  const float cz = new_xyz[(size_t)wave * 3 + 2];
  const float cc = __fadd_rn(__fadd_rn(__fmul_rn(cx, cx), __fmul_rn(cy, cy)), __fmul_rn(cz, cz));
  float ldd[16]; int ldi[16];
#pragma unroll
  for (int q = 0; q < 16; ++q) { ldd[q] = 3.4e38f; ldi[q] = 0x7fffffff; }
  for (int i = 0; i < 64; ++i) {
    int j = i * 64 + t;  // coalesced across lanes
    float4 p = P[j];
    float dot = __fadd_rn(__fadd_rn(__fmul_rn(cx, p.x), __fmul_rn(cy, p.y)), __fmul_rn(cz, p.z));
    float d = __fsub_rn(__fadd_rn(cc, p.w), __fmul_rn(2.0f, dot));
    if (d < ldd[15] || (d == ldd[15] && j < ldi[15])) {
      float cd = d; int ci = j;
#pragma unroll
      for (int q = 0; q < 16; ++q) {
        bool sw = (cd < ldd[q]) || (cd == ldd[q] && ci < ldi[q]);
        float td = ldd[q]; int ti = ldi[q];
        if (sw) { ldd[q] = cd; ldi[q] = ci; cd = td; ci = ti; }
      }
    }
  }
  // 16-pop wave merge of 64 sorted lists
  float cd = ldd[0]; int ci = ldi[0];
  int* op = knn_idx + (size_t)wave * 16;
#pragma unroll 1
  for (int k = 0; k < 16; ++k) {
    float wd = cd; int wi = ci;
#pragma unroll
    for (int off = 1; off < 64; off <<= 1) {
      float ov = __shfl_xor(wd, off);
      int   oi = __shfl_xor(wi, off);
      bool tk = (ov < wd) || (ov == wd && oi < wi);
      wd = tk ? ov : wd; wi = tk ? oi : wi;
    }
    if (t == 0) op[k] = wi;
    if (wd == cd && wi == ci) {  // this lane's head was popped
#pragma unroll
      for (int q = 0; q < 15; ++q) { ldd[q] = ldd[q + 1]; ldi[q] = ldi[q + 1]; }
      ldd[15] = 3.4e38f; ldi[15] = 0x7fffffff;
    }
    cd = ldd[0]; ci = ldi[0];
  }
}

// ---------------- gather + mlp1: 512 blocks x 256 threads ----------------
__global__ __launch_bounds__(256) void mlp1_kernel(const float* __restrict__ feat,
                                                   const int* __restrict__ knn_idx,
                                                   const float* __restrict__ w1,
                                                   const float* __restrict__ b1,
                                                   float* __restrict__ x1) {
  __shared__ float w1s[64 * 64];
  __shared__ float b1s[64];
  const int t = threadIdx.x;
  for (int i = t; i < 4096; i += 256) w1s[i] = w1[i];
  if (t < 64) b1s[t] = b1[t];
  __syncthreads();
  const int pos = blockIdx.x * 256 + t;
  const int b = pos >> 14;
  const int n = knn_idx[pos];
  const float4* fp = reinterpret_cast<const float4*>(feat + ((size_t)(b * 4096 + n)) * 64);
  float4 fr[16];
#pragma unroll
  for (int i = 0; i < 16; ++i) fr[i] = fp[i];
  float4* op = reinterpret_cast<float4*>(x1 + (size_t)pos * 64);
#pragma unroll
  for (int cq = 0; cq < 16; ++cq) {
    float a0 = b1s[cq * 4 + 0], a1 = b1s[cq * 4 + 1], a2 = b1s[cq * 4 + 2], a3 = b1s[cq * 4 + 3];
#pragma unroll
    for (int iq = 0; iq < 16; ++iq) {
      float4 f4 = fr[iq];
      float4 wa = *reinterpret_cast<const float4*>(&w1s[(cq * 4 + 0) * 64 + iq * 4]);
      float4 wb = *reinterpret_cast<const float4*>(&w1s[(cq * 4 + 1) * 64 + iq * 4]);
      float4 wc = *reinterpret_cast<const float4*>(&w1s[(cq * 4 + 2) * 64 + iq * 4]);
      float4 wd = *reinterpret_cast<const float4*>(&w1s[(cq * 4 + 3) * 64 + iq * 4]);
      a0 += f4.x * wa.x + f4.y * wa.y + f4.z * wa.z + f4.w * wa.w;
      a1 += f4.x * wb.x + f4.y * wb.y + f4.z * wb.z + f4.w * wb.w;
      a2 += f4.x * wc.x + f4.y * wc.y + f4.z * wc.z + f4.w * wc.w;
      a3 += f4.x * wd.x + f4.y * wd.y + f4.z * wd.z + f4.w * wd.w;
    }
    op[cq] = make_float4(a0, a1, a2, a3);
  }
}

// ---------------- BN1 stats: 512 blocks x 256 ----------------
__global__ __launch_bounds__(256) void bn1_stats_kernel(const float* __restrict__ x1,
                                                        float* __restrict__ bnp1) {
  __shared__ float ls[4][64], lq[4][64];
  const int t = threadIdx.x, c = t & 63, g = t >> 6;
  const float* p = x1 + ((size_t)blockIdx.x * 256 + g * 64) * 64 + c;
  float s = 0.f, s2 = 0.f;
  for (int i = 0; i < 64; ++i) { float v = p[(size_t)i * 64]; s += v; s2 = fmaf(v, v, s2); }
  ls[g][c] = s; lq[g][c] = s2;
  __syncthreads();
  if (t < 64) {
    bnp1[blockIdx.x * 128 + t]      = ls[0][t] + ls[1][t] + ls[2][t] + ls[3][t];
    bnp1[blockIdx.x * 128 + 64 + t] = lq[0][t] + lq[1][t] + lq[2][t] + lq[3][t];
  }
}

__global__ void bn1_final_kernel(const float* __restrict__ bnp1, const float* __restrict__ g1,
                                 const float* __restrict__ bt1, float* __restrict__ bn1s) {
  int c = threadIdx.x;  // 64
  float S = 0.f, Q = 0.f;
  for (int i = 0; i < 512; ++i) { S += bnp1[i * 128 + c]; Q += bnp1[i * 128 + 64 + c]; }
  float m = S * (1.0f / 131072.0f);
  float var = Q * (1.0f / 131072.0f) - m * m;
  float sc = g1[c] * rsqrtf(var + EPSBN);
  bn1s[c] = sc;
  bn1s[64 + c] = bt1[c] - m * sc;
}

// ---------------- fused transformer (rank-64 collapsed): 8192 blocks x 64 ----------------
__global__ __launch_bounds__(64) void transformer_fused(
    float* __restrict__ x1, const float* __restrict__ bn1s,
    const float* __restrict__ G, const float* __restrict__ u, const float* __restrict__ w,
    const float* __restrict__ cc, const float* __restrict__ ZT, const float* __restrict__ tb) {
  __shared__ float pre[16][65];
  __shared__ float ts[16][65];
  __shared__ float ys[16][65];
  __shared__ float ss[16][17];
  __shared__ float spu[16], spw[16];
  const int c = threadIdx.x;
  const size_t base = (size_t)blockIdx.x * 1024;
  const float sc = bn1s[c], sh = bn1s[64 + c];
  float pc[16];
#pragma unroll
  for (int k = 0; k < 16; ++k) {
    float v = x1[base + k * 64 + c];
    float p = fmaxf(0.f, v * sc + sh);
    pc[k] = p; pre[k][c] = p;
  }
  __syncthreads();
  float tcol[16], ycol[16];
#pragma unroll
  for (int k = 0; k < 16; ++k) { tcol[k] = 0.f; ycol[k] = 0.f; }
  for (int i = 0; i < 64; ++i) {
    float g = G[i * 64 + c];
    float z = ZT[i * 64 + c];
#pragma unroll
    for (int k = 0; k < 16; ++k) {
      float p = pre[k][i];
      tcol[k] = fmaf(p, g, tcol[k]);
      ycol[k] = fmaf(p, z, ycol[k]);
    }
  }
#pragma unroll
  for (int k = 0; k < 16; ++k) { ts[k][c] = tcol[k]; ys[k][c] = ycol[k]; }
  if (c < 16) {
    float s = 0.f;
    for (int i = 0; i < 64; ++i) s = fmaf(pre[c][i], u[i], s);
    spu[c] = s;
  } else if (c < 32) {
    int m = c - 16; float s = 0.f;
    for (int i = 0; i < 64; ++i) s = fmaf(pre[m][i], w[i], s);
    spw[m] = s;
  }
  __syncthreads();
  {
    const float cval = cc[0];
    const int m = c & 15, nb = c >> 4;
#pragma unroll
    for (int ng = 0; ng < 4; ++ng) {
      int n = ng * 4 + nb;
      float s = 0.f;
      for (int i = 0; i < 64; ++i) s = fmaf(ts[n][i], pre[m][i], s);
      ss[n][m] = s + spu[n] + spw[m] + cval;
    }
  }
  __syncthreads();
  if (c < 16) {
    float mx = -3.4e38f;
#pragma unroll
    for (int m = 0; m < 16; ++m) mx = fmaxf(mx, ss[c][m]);
    float e[16], sum = 0.f;
#pragma unroll
    for (int m = 0; m < 16; ++m) { e[m] = expf(ss[c][m] - mx); sum += e[m]; }
    float r = 1.0f / sum;
#pragma unroll
    for (int m = 0; m < 16; ++m) ss[c][m] = e[m] * r;
  }
  __syncthreads();
  const float tbc = tb[c];
  float o[16];
#pragma unroll
  for (int k = 0; k < 16; ++k) o[k] = 0.f;
#pragma unroll
  for (int m = 0; m < 16; ++m) {
    float yv = ys[m][c];
#pragma unroll
    for (int k = 0; k < 16; ++k) o[k] = fmaf(ss[k][m], yv, o[k]);
  }
#pragma unroll
  for (int k = 0; k < 16; ++k) x1[base + k * 64 + c] = o[k] + tbc + pc[k];
}

// ---------------- BN2 stats (computes mlp2 on the fly): 1024 blocks x 256 ----------------
__global__ __launch_bounds__(256) void bn2_stats_kernel(const float* __restrict__ x2,
                                                        const float* __restrict__ w2,
                                                        const float* __restrict__ b2,
                                                        float* __restrict__ bnp2) {
  __shared__ float sx2[128 * 64];
  __shared__ float ps[2][128], pq[2][128];
  const int t = threadIdx.x;
  const float4* s4 = reinterpret_cast<const float4*>(x2 + (size_t)blockIdx.x * 128 * 64);
  float4* d4 = reinterpret_cast<float4*>(sx2);
  for (int i = 0; i < 8; ++i) d4[i * 256 + t] = s4[i * 256 + t];
  __syncthreads();
  const int c = t & 127, h = t >> 7;
  float4 wreg[16];
  const float4* w4 = reinterpret_cast<const float4*>(w2 + c * 64);
#pragma unroll
  for (int i = 0; i < 16; ++i) wreg[i] = w4[i];
  const float bb = b2[c];
  float s = 0.f, q = 0.f;
  for (int p = 0; p < 64; ++p) {
    const float4* xr = reinterpret_cast<const float4*>(&sx2[(h * 64 + p) * 64]);
    float acc = bb;
#pragma unroll
    for (int i = 0; i < 16; ++i) {
      float4 xv = xr[i];
      acc += xv.x * wreg[i].x + xv.y * wreg[i].y + xv.z * wreg[i].z + xv.w * wreg[i].w;
    }
    s += acc; q = fmaf(acc, acc, q);
  }
  ps[h][c] = s; pq[h][c] = q;
  __syncthreads();
  if (t < 128) {
    bnp2[blockIdx.x * 256 + t]       = ps[0][t] + ps[1][t];
    bnp2[blockIdx.x * 256 + 128 + t] = pq[0][t] + pq[1][t];
  }
}

__global__ void bn2_final_kernel(const float* __restrict__ bnp2, const float* __restrict__ g2,
                                 const float* __restrict__ bt2, float* __restrict__ bn2s) {
  int c = threadIdx.x;  // 128
  float S = 0.f, Q = 0.f;
  for (int i = 0; i < 1024; ++i) { S += bnp2[i * 256 + c]; Q += bnp2[i * 256 + 128 + c]; }
  float m = S * (1.0f / 131072.0f);
  float var = Q * (1.0f / 131072.0f) - m * m;
  float sc = g2[c] * rsqrtf(var + EPSBN);
  bn2s[c] = sc;
  bn2s[128 + c] = bt2[c] - m * sc;
}

// ---------------- final: mlp2 + BN2 + ReLU + maxpool: 8192 blocks x 128 ----------------
__global__ __launch_bounds__(128) void final_kernel(const float* __restrict__ x2,
                                                    const float* __restrict__ w2,
                                                    const float* __restrict__ b2,
                                                    const float* __restrict__ bn2s,
                                                    float* __restrict__ out) {
  __shared__ float sx2[16 * 64];
  const int t = threadIdx.x;
  const float4* s4 = reinterpret_cast<const float4*>(x2 + (size_t)blockIdx.x * 1024);
  float4* d4 = reinterpret_cast<float4*>(sx2);
  for (int i = 0; i < 2; ++i) d4[i * 128 + t] = s4[i * 128 + t];
  __syncthreads();
  const int c = t;
  float4 wreg[16];
  const float4* w4 = reinterpret_cast<const float4*>(w2 + c * 64);
#pragma unroll
  for (int i = 0; i < 16; ++i) wreg[i] = w4[i];
  const float bb = b2[c], sc = bn2s[c], sh = bn2s[128 + c];
  float mx = -3.4e38f;
  for (int k = 0; k < 16; ++k) {
    const float4* xr = reinterpret_cast<const float4*>(&sx2[k * 64]);
    float acc = bb;
#pragma unroll
    for (int i = 0; i < 16; ++i) {
      float4 xv = xr[i];
      acc += xv.x * wreg[i].x + xv.y * wreg[i].y + xv.z * wreg[i].z + xv.w * wreg[i].w;
    }
    float y = fmaxf(0.f, acc * sc + sh);
    mx = fmaxf(mx, y);
  }
  out[24576 + (size_t)blockIdx.x * 128 + c] = mx;
}

// ---------------- launch ----------------
extern "C" void kernel_launch(void* const* d_in, const int* in_sizes, int n_in,
                              void* d_out, int out_size, void* d_ws, size_t ws_size,
                              hipStream_t stream) {
  const float* xyz  = (const float*)d_in[0];
  const float* feat = (const float*)d_in[1];
  const float* w1   = (const float*)d_in[2];
  const float* b1   = (const float*)d_in[3];
  const float* g1   = (const float*)d_in[4];
  const float* bt1  = (const float*)d_in[5];
  const float* fc1w = (const float*)d_in[6];
  const float* fc1b = (const float*)d_in[7];
  const float* wq   = (const float*)d_in[8];
  const float* wk   = (const float*)d_in[9];
  const float* wv   = (const float*)d_in[10];
  const float* fc2w = (const float*)d_in[11];
  const float* fc2b = (const float*)d_in[12];
  const float* w2   = (const float*)d_in[13];
  const float* b2   = (const float*)d_in[14];
  const float* g2   = (const float*)d_in[15];
  const float* bt2  = (const float*)d_in[16];
  float* out = (float*)d_out;
  char* ws = (char*)d_ws;

  int*    knn_idx = (int*)(ws + WS_KNN_IDX);
  float*  x1      = (float*)(ws + WS_X1);
  float*  bnp1    = (float*)(ws + WS_BNP1);
  float*  bn1s    = (float*)(ws + WS_BN1S);
  float*  bnp2    = (float*)(ws + WS_BNP2);
  float*  bn2s    = (float*)(ws + WS_BN2S);
  float*  Abuf    = (float*)(ws + WS_A);
  float*  Bbuf    = (float*)(ws + WS_B);
  float*  qb      = (float*)(ws + WS_QB);
  float*  kb      = (float*)(ws + WS_KB);
  float*  Wc      = (float*)(ws + WS_WC);
  float*  G       = (float*)(ws + WS_G);
  float*  ZT      = (float*)(ws + WS_ZT);
  float*  u       = (float*)(ws + WS_U);
  float*  w       = (float*)(ws + WS_W);
  float*  tb      = (float*)(ws + WS_TB);
  float*  cc      = (float*)(ws + WS_CC);
  float4* pts4    = (float4*)(ws + WS_PTS4);

  prep_AB<<<256, 256, 0, stream>>>(wq, wk, fc1w, fc1b, Abuf, Bbuf, qb, kb);
  prep_Wc<<<128, 256, 0, stream>>>(fc2w, wv, Wc);
  prep_G<<<17, 256, 0, stream>>>(Abuf, Bbuf, qb, kb, G, u, w, cc);
  prep_Z<<<17, 256, 0, stream>>>(Wc, fc1w, fc1b, fc2b, ZT, tb);
  pack_pts_kernel<<<128, 256, 0, stream>>>(xyz, pts4);

  fps_kernel<<<8, 512, 0, stream>>>(xyz, out);
  knn_kernel<<<2048, 256, 0, stream>>>(pts4, out, knn_idx);
  mlp1_kernel<<<512, 256, 0, stream>>>(feat, knn_idx, w1, b1, x1);
  bn1_stats_kernel<<<512, 256, 0, stream>>>(x1, bnp1);
  bn1_final_kernel<<<1, 64, 0, stream>>>(bnp1, g1, bt1, bn1s);
  transformer_fused<<<8192, 64, 0, stream>>>(x1, bn1s, G, u, w, cc, ZT, tb);
  bn2_stats_kernel<<<1024, 256, 0, stream>>>(x1, w2, b2, bnp2);
  bn2_final_kernel<<<1, 128, 0, stream>>>(bnp2, g2, bt2, bn2s);
  final_kernel<<<8192, 128, 0, stream>>>(x1, w2, b2, bn2s, out);
}

// Round 4
// 1377.919 us; speedup vs baseline: 8.8610x; 1.9779x over previous
//
#include <hip/hip_runtime.h>

// ---------------- sizes ----------------
// B=8, N=4096, S=1024, K=16, C1=64, D=512, C2=128
// positions P = 8*1024*16 = 131072
#define EPSBN 1e-5f
#define INVSQ 0.04419417382415922f  // 1/sqrt(512)

// ---------------- ws byte offsets ----------------
#define WS_KNN_IDX   32768u       // 131072*4          = 524288
#define WS_X1        1048576u     // 131072*64*4       = 33554432 (also holds x2 in-place)
#define WS_BNP1      34603008u    // 512*128*4         = 262144
#define WS_BN1S      34865152u    // 128*4             = 512
#define WS_BNP2      34865664u    // 1024*256*4        = 1048576
#define WS_BN2S      35914240u    // 256*4             = 1024
#define WS_A         35915264u    // 512*64*4          = 131072
#define WS_B         36046336u    // 512*64*4
#define WS_QB        36177408u    // 512*4
#define WS_KB        36179456u    // 512*4
#define WS_WC        36181504u    // 64*512*4          = 131072
#define WS_G         36312576u    // 64*64*4           = 16384
#define WS_ZT        36328960u    // 64*64*4
#define WS_U         36345344u    // 64*4
#define WS_W         36345600u
#define WS_TB        36345856u
#define WS_CC        36346112u    // 4
#define WS_PTS4      36346368u    // 32768*16          = 524288 (end ~36.9MB)

// ---------------- prep1: weight combines stage 1 + point packing ----------------
// blocks 0..255: A=wq@fc1w, B=wk@fc1w, qb, kb
// blocks 256..383: Wc = fc2w@wv
// blocks 384..511: pack (x,y,z,|p|^2)
__global__ __launch_bounds__(256) void prep1_kernel(const float* __restrict__ wq,
                                                    const float* __restrict__ wk,
                                                    const float* __restrict__ fc1w,
                                                    const float* __restrict__ fc1b,
                                                    const float* __restrict__ fc2w,
                                                    const float* __restrict__ wv,
                                                    const float* __restrict__ xyz,
                                                    float* __restrict__ A, float* __restrict__ B,
                                                    float* __restrict__ qb, float* __restrict__ kb,
                                                    float* __restrict__ Wc,
                                                    float4* __restrict__ pts4) {
  const int blk = blockIdx.x;
  if (blk < 256) {
    int id = blk * 256 + threadIdx.x;  // 0..65535
    int which = id >> 15;
    int rem = id & 32767;
    int r = rem >> 6, i = rem & 63;
    const float* W = which ? wk : wq;
    float s = 0.f;
    for (int d = 0; d < 512; ++d) s = fmaf(W[r * 512 + d], fc1w[d * 64 + i], s);
    (which ? B : A)[r * 64 + i] = s;
    if (i == 0) {
      float sb = 0.f;
      for (int d = 0; d < 512; ++d) sb = fmaf(W[r * 512 + d], fc1b[d], sb);
      (which ? kb : qb)[r] = sb;
    }
  } else if (blk < 384) {
    int id = (blk - 256) * 256 + threadIdx.x;  // 0..32767
    int c = id >> 9, d = id & 511;
    float s = 0.f;
    for (int e = 0; e < 512; ++e) s = fmaf(fc2w[c * 512 + e], wv[e * 512 + d], s);
    Wc[c * 512 + d] = s;
  } else {
    int id = (blk - 384) * 256 + threadIdx.x;  // 0..32767
    float x = xyz[id * 3 + 0], y = xyz[id * 3 + 1], z = xyz[id * 3 + 2];
    float pp = __fadd_rn(__fadd_rn(__fmul_rn(x, x), __fmul_rn(y, y)), __fmul_rn(z, z));
    pts4[id] = make_float4(x, y, z, pp);
  }
}

// ---------------- prep2: weight combines stage 2 ----------------
// blocks 0..16: G, u, w, cc ; blocks 17..33: ZT, tb
__global__ __launch_bounds__(256) void prep2_kernel(const float* __restrict__ A,
                                                    const float* __restrict__ B,
                                                    const float* __restrict__ qb,
                                                    const float* __restrict__ kb,
                                                    const float* __restrict__ Wc,
                                                    const float* __restrict__ fc1w,
                                                    const float* __restrict__ fc1b,
                                                    const float* __restrict__ fc2b,
                                                    float* __restrict__ G, float* __restrict__ u,
                                                    float* __restrict__ w, float* __restrict__ cc,
                                                    float* __restrict__ ZT, float* __restrict__ tb) {
  const int blk = blockIdx.x;
  if (blk < 17) {
    int id = blk * 256 + threadIdx.x;
    if (id < 4096) {
      int i = id >> 6, j = id & 63;
      float s = 0.f;
      for (int d = 0; d < 512; ++d) s = fmaf(A[d * 64 + i], B[d * 64 + j], s);
      G[i * 64 + j] = s * INVSQ;
    } else if (id < 4160) {
      int i = id - 4096; float s = 0.f;
      for (int d = 0; d < 512; ++d) s = fmaf(A[d * 64 + i], kb[d], s);
      u[i] = s * INVSQ;
    } else if (id < 4224) {
      int j = id - 4160; float s = 0.f;
      for (int d = 0; d < 512; ++d) s = fmaf(B[d * 64 + j], qb[d], s);
      w[j] = s * INVSQ;
    } else if (id == 4224) {
      float s = 0.f;
      for (int d = 0; d < 512; ++d) s = fmaf(qb[d], kb[d], s);
      cc[0] = s * INVSQ;
    }
  } else {
    int id = (blk - 17) * 256 + threadIdx.x;
    if (id < 4096) {
      int i = id >> 6, c = id & 63;
      float s = 0.f;
      for (int d = 0; d < 512; ++d) s = fmaf(Wc[c * 512 + d], fc1w[d * 64 + i], s);
      ZT[i * 64 + c] = s;
    } else if (id < 4160) {
      int c = id - 4096; float s = 0.f;
      for (int d = 0; d < 512; ++d) s = fmaf(Wc[c * 512 + d], fc1b[d], s);
      tb[c] = s + fc2b[c];
    }
  }
}

// ---------------- FPS: 8 blocks x 256 threads, DPP wave-reduce on packed u64 ----------------
// key = (float_bits(dist) << 32) | (4095 - idx)  -> max key == max dist, min idx on ties
#define FPS_REDSTEP(CTRL)                                                              \
  {                                                                                    \
    unsigned lo2 = (unsigned)__builtin_amdgcn_update_dpp(0, (int)klo, CTRL, 0xF, 0xF, true); \
    unsigned hi2 = (unsigned)__builtin_amdgcn_update_dpp(0, (int)khi, CTRL, 0xF, 0xF, true); \
    bool tk = (hi2 > khi) || (hi2 == khi && lo2 > klo);                                \
    khi = tk ? hi2 : khi; klo = tk ? lo2 : klo;                                        \
  }

__global__ __launch_bounds__(256) void fps_kernel(const float4* __restrict__ pts4,
                                                  float* __restrict__ out_xyz) {
  __shared__ float4 spts[4096];                 // 64 KB
  __shared__ unsigned long long red[2][4];      // [parity][wave]
  const int b = blockIdx.x;
  const int t = threadIdx.x;
  const int lane = t & 63, wid = t >> 6;
  const float4* pb = pts4 + (size_t)b * 4096;
  float px[16], py[16], pz[16], pd[16];
#pragma unroll
  for (int i = 0; i < 16; ++i) {
    int j = i * 256 + t;
    float4 p = pb[j];
    spts[j] = p;
    px[i] = p.x; py[i] = p.y; pz[i] = p.z; pd[i] = 1e10f;
  }
  __syncthreads();
  float4 c4 = spts[0];
  for (int it = 0; it < 1024; ++it) {
    if (t == 0) {
      out_xyz[(size_t)(b * 1024 + it) * 3 + 0] = c4.x;
      out_xyz[(size_t)(b * 1024 + it) * 3 + 1] = c4.y;
      out_xyz[(size_t)(b * 1024 + it) * 3 + 2] = c4.z;
    }
    // distance update + in-lane argmax (first-max kept: ascending j within lane)
    float bv = -1.0f; int bj = 0;
#pragma unroll
    for (int i = 0; i < 16; ++i) {
      float dx = __fsub_rn(px[i], c4.x);
      float dy = __fsub_rn(py[i], c4.y);
      float dz = __fsub_rn(pz[i], c4.z);
      float d = __fadd_rn(__fadd_rn(__fmul_rn(dx, dx), __fmul_rn(dy, dy)), __fmul_rn(dz, dz));
      float nd = fminf(pd[i], d);
      pd[i] = nd;
      bool g = nd > bv;
      bv = g ? nd : bv;
      bj = g ? (i * 256 + t) : bj;
    }
    // pack key
    unsigned klo = 4095u - (unsigned)bj;
    unsigned khi = __float_as_uint(bv);
    // DPP wave64 max-reduce (VALU only); result lands in lane 63
    FPS_REDSTEP(0x111)  // row_shr:1
    FPS_REDSTEP(0x112)  // row_shr:2
    FPS_REDSTEP(0x114)  // row_shr:4
    FPS_REDSTEP(0x118)  // row_shr:8
    FPS_REDSTEP(0x142)  // row_bcast:15
    FPS_REDSTEP(0x143)  // row_bcast:31
    unsigned wlo = (unsigned)__builtin_amdgcn_readlane((int)klo, 63);
    unsigned whi = (unsigned)__builtin_amdgcn_readlane((int)khi, 63);
    const int p = it & 1;
    if (lane == 0) red[p][wid] = (((unsigned long long)whi) << 32) | wlo;
    __syncthreads();
    // cross-wave combine (4 u64 broadcast reads)
    unsigned long long k0 = red[p][0];
#pragma unroll
    for (int w = 1; w < 4; ++w) {
      unsigned long long kw = red[p][w];
      k0 = (kw > k0) ? kw : k0;
    }
    int jw = 4095 - (int)(unsigned)(k0 & 0xFFFFFFFFull);
    c4 = spts[jw];  // uniform broadcast read
  }
}

// ---------------- kNN: one wave per center, 2048 blocks x 256, no LDS ----------------
__global__ __launch_bounds__(256) void knn_kernel(const float4* __restrict__ pts4,
                                                  const float* __restrict__ new_xyz,
                                                  int* __restrict__ knn_idx) {
  const int t = threadIdx.x & 63;
  const int wave = (blockIdx.x << 2) | (threadIdx.x >> 6);  // center id 0..8191
  const int b = wave >> 10;
  const float4* P = pts4 + (size_t)b * 4096;
  const float cx = new_xyz[(size_t)wave * 3 + 0];
  const float cy = new_xyz[(size_t)wave * 3 + 1];
  const float cz = new_xyz[(size_t)wave * 3 + 2];
  const float cc = __fadd_rn(__fadd_rn(__fmul_rn(cx, cx), __fmul_rn(cy, cy)), __fmul_rn(cz, cz));
  float ldd[16]; int ldi[16];
#pragma unroll
  for (int q = 0; q < 16; ++q) { ldd[q] = 3.4e38f; ldi[q] = 0x7fffffff; }
  for (int i = 0; i < 64; ++i) {
    int j = i * 64 + t;  // coalesced across lanes
    float4 p = P[j];
    float dot = __fadd_rn(__fadd_rn(__fmul_rn(cx, p.x), __fmul_rn(cy, p.y)), __fmul_rn(cz, p.z));
    float d = __fsub_rn(__fadd_rn(cc, p.w), __fmul_rn(2.0f, dot));
    if (d < ldd[15] || (d == ldd[15] && j < ldi[15])) {
      float cd = d; int ci = j;
#pragma unroll
      for (int q = 0; q < 16; ++q) {
        bool sw = (cd < ldd[q]) || (cd == ldd[q] && ci < ldi[q]);
        float td = ldd[q]; int ti = ldi[q];
        if (sw) { ldd[q] = cd; ldi[q] = ci; cd = td; ci = ti; }
      }
    }
  }
  // 16-pop wave merge of 64 sorted lists
  float cd = ldd[0]; int ci = ldi[0];
  int* op = knn_idx + (size_t)wave * 16;
#pragma unroll 1
  for (int k = 0; k < 16; ++k) {
    float wd = cd; int wi = ci;
#pragma unroll
    for (int off = 1; off < 64; off <<= 1) {
      float ov = __shfl_xor(wd, off);
      int   oi = __shfl_xor(wi, off);
      bool tk = (ov < wd) || (ov == wd && oi < wi);
      wd = tk ? ov : wd; wi = tk ? oi : wi;
    }
    if (t == 0) op[k] = wi;
    if (wd == cd && wi == ci) {  // this lane's head was popped
#pragma unroll
      for (int q = 0; q < 15; ++q) { ldd[q] = ldd[q + 1]; ldi[q] = ldi[q + 1]; }
      ldd[15] = 3.4e38f; ldi[15] = 0x7fffffff;
    }
    cd = ldd[0]; ci = ldi[0];
  }
}

// ---------------- gather + mlp1: 512 blocks x 256 threads ----------------
__global__ __launch_bounds__(256) void mlp1_kernel(const float* __restrict__ feat,
                                                   const int* __restrict__ knn_idx,
                                                   const float* __restrict__ w1,
                                                   const float* __restrict__ b1,
                                                   float* __restrict__ x1) {
  __shared__ float w1s[64 * 64];
  __shared__ float b1s[64];
  const int t = threadIdx.x;
  for (int i = t; i < 4096; i += 256) w1s[i] = w1[i];
  if (t < 64) b1s[t] = b1[t];
  __syncthreads();
  const int pos = blockIdx.x * 256 + t;
  const int b = pos >> 14;
  const int n = knn_idx[pos];
  const float4* fp = reinterpret_cast<const float4*>(feat + ((size_t)(b * 4096 + n)) * 64);
  float4 fr[16];
#pragma unroll
  for (int i = 0; i < 16; ++i) fr[i] = fp[i];
  float4* op = reinterpret_cast<float4*>(x1 + (size_t)pos * 64);
#pragma unroll
  for (int cq = 0; cq < 16; ++cq) {
    float a0 = b1s[cq * 4 + 0], a1 = b1s[cq * 4 + 1], a2 = b1s[cq * 4 + 2], a3 = b1s[cq * 4 + 3];
#pragma unroll
    for (int iq = 0; iq < 16; ++iq) {
      float4 f4 = fr[iq];
      float4 wa = *reinterpret_cast<const float4*>(&w1s[(cq * 4 + 0) * 64 + iq * 4]);
      float4 wb = *reinterpret_cast<const float4*>(&w1s[(cq * 4 + 1) * 64 + iq * 4]);
      float4 wc = *reinterpret_cast<const float4*>(&w1s[(cq * 4 + 2) * 64 + iq * 4]);
      float4 wd = *reinterpret_cast<const float4*>(&w1s[(cq * 4 + 3) * 64 + iq * 4]);
      a0 += f4.x * wa.x + f4.y * wa.y + f4.z * wa.z + f4.w * wa.w;
      a1 += f4.x * wb.x + f4.y * wb.y + f4.z * wb.z + f4.w * wb.w;
      a2 += f4.x * wc.x + f4.y * wc.y + f4.z * wc.z + f4.w * wc.w;
      a3 += f4.x * wd.x + f4.y * wd.y + f4.z * wd.z + f4.w * wd.w;
    }
    op[cq] = make_float4(a0, a1, a2, a3);
  }
}

// ---------------- BN1 stats: 512 blocks x 256 ----------------
__global__ __launch_bounds__(256) void bn1_stats_kernel(const float* __restrict__ x1,
                                                        float* __restrict__ bnp1) {
  __shared__ float ls[4][64], lq[4][64];
  const int t = threadIdx.x, c = t & 63, g = t >> 6;
  const float* p = x1 + ((size_t)blockIdx.x * 256 + g * 64) * 64 + c;
  float s = 0.f, s2 = 0.f;
  for (int i = 0; i < 64; ++i) { float v = p[(size_t)i * 64]; s += v; s2 = fmaf(v, v, s2); }
  ls[g][c] = s; lq[g][c] = s2;
  __syncthreads();
  if (t < 64) {
    bnp1[blockIdx.x * 128 + t]      = ls[0][t] + ls[1][t] + ls[2][t] + ls[3][t];
    bnp1[blockIdx.x * 128 + 64 + t] = lq[0][t] + lq[1][t] + lq[2][t] + lq[3][t];
  }
}

__global__ void bn1_final_kernel(const float* __restrict__ bnp1, const float* __restrict__ g1,
                                 const float* __restrict__ bt1, float* __restrict__ bn1s) {
  int c = threadIdx.x;  // 64
  float S = 0.f, Q = 0.f;
  for (int i = 0; i < 512; ++i) { S += bnp1[i * 128 + c]; Q += bnp1[i * 128 + 64 + c]; }
  float m = S * (1.0f / 131072.0f);
  float var = Q * (1.0f / 131072.0f) - m * m;
  float sc = g1[c] * rsqrtf(var + EPSBN);
  bn1s[c] = sc;
  bn1s[64 + c] = bt1[c] - m * sc;
}

// ---------------- fused transformer (rank-64 collapsed): 8192 blocks x 64 ----------------
__global__ __launch_bounds__(64) void transformer_fused(
    float* __restrict__ x1, const float* __restrict__ bn1s,
    const float* __restrict__ G, const float* __restrict__ u, const float* __restrict__ w,
    const float* __restrict__ cc, const float* __restrict__ ZT, const float* __restrict__ tb) {
  __shared__ float pre[16][65];
  __shared__ float ts[16][65];
  __shared__ float ys[16][65];
  __shared__ float ss[16][17];
  __shared__ float spu[16], spw[16];
  const int c = threadIdx.x;
  const size_t base = (size_t)blockIdx.x * 1024;
  const float sc = bn1s[c], sh = bn1s[64 + c];
  float pc[16];
#pragma unroll
  for (int k = 0; k < 16; ++k) {
    float v = x1[base + k * 64 + c];
    float p = fmaxf(0.f, v * sc + sh);
    pc[k] = p; pre[k][c] = p;
  }
  __syncthreads();
  float tcol[16], ycol[16];
#pragma unroll
  for (int k = 0; k < 16; ++k) { tcol[k] = 0.f; ycol[k] = 0.f; }
  for (int i = 0; i < 64; ++i) {
    float g = G[i * 64 + c];
    float z = ZT[i * 64 + c];
#pragma unroll
    for (int k = 0; k < 16; ++k) {
      float p = pre[k][i];
      tcol[k] = fmaf(p, g, tcol[k]);
      ycol[k] = fmaf(p, z, ycol[k]);
    }
  }
#pragma unroll
  for (int k = 0; k < 16; ++k) { ts[k][c] = tcol[k]; ys[k][c] = ycol[k]; }
  if (c < 16) {
    float s = 0.f;
    for (int i = 0; i < 64; ++i) s = fmaf(pre[c][i], u[i], s);
    spu[c] = s;
  } else if (c < 32) {
    int m = c - 16; float s = 0.f;
    for (int i = 0; i < 64; ++i) s = fmaf(pre[m][i], w[i], s);
    spw[m] = s;
  }
  __syncthreads();
  {
    const float cval = cc[0];
    const int m = c & 15, nb = c >> 4;
#pragma unroll
    for (int ng = 0; ng < 4; ++ng) {
      int n = ng * 4 + nb;
      float s = 0.f;
      for (int i = 0; i < 64; ++i) s = fmaf(ts[n][i], pre[m][i], s);
      ss[n][m] = s + spu[n] + spw[m] + cval;
    }
  }
  __syncthreads();
  if (c < 16) {
    float mx = -3.4e38f;
#pragma unroll
    for (int m = 0; m < 16; ++m) mx = fmaxf(mx, ss[c][m]);
    float e[16], sum = 0.f;
#pragma unroll
    for (int m = 0; m < 16; ++m) { e[m] = expf(ss[c][m] - mx); sum += e[m]; }
    float r = 1.0f / sum;
#pragma unroll
    for (int m = 0; m < 16; ++m) ss[c][m] = e[m] * r;
  }
  __syncthreads();
  const float tbc = tb[c];
  float o[16];
#pragma unroll
  for (int k = 0; k < 16; ++k) o[k] = 0.f;
#pragma unroll
  for (int m = 0; m < 16; ++m) {
    float yv = ys[m][c];
#pragma unroll
    for (int k = 0; k < 16; ++k) o[k] = fmaf(ss[k][m], yv, o[k]);
  }
#pragma unroll
  for (int k = 0; k < 16; ++k) x1[base + k * 64 + c] = o[k] + tbc + pc[k];
}

// ---------------- BN2 stats (computes mlp2 on the fly): 1024 blocks x 256 ----------------
__global__ __launch_bounds__(256) void bn2_stats_kernel(const float* __restrict__ x2,
                                                        const float* __restrict__ w2,
                                                        const float* __restrict__ b2,
                                                        float* __restrict__ bnp2) {
  __shared__ float sx2[128 * 64];
  __shared__ float ps[2][128], pq[2][128];
  const int t = threadIdx.x;
  const float4* s4 = reinterpret_cast<const float4*>(x2 + (size_t)blockIdx.x * 128 * 64);
  float4* d4 = reinterpret_cast<float4*>(sx2);
  for (int i = 0; i < 8; ++i) d4[i * 256 + t] = s4[i * 256 + t];
  __syncthreads();
  const int c = t & 127, h = t >> 7;
  float4 wreg[16];
  const float4* w4 = reinterpret_cast<const float4*>(w2 + c * 64);
#pragma unroll
  for (int i = 0; i < 16; ++i) wreg[i] = w4[i];
  const float bb = b2[c];
  float s = 0.f, q = 0.f;
  for (int p = 0; p < 64; ++p) {
    const float4* xr = reinterpret_cast<const float4*>(&sx2[(h * 64 + p) * 64]);
    float acc = bb;
#pragma unroll
    for (int i = 0; i < 16; ++i) {
      float4 xv = xr[i];
      acc += xv.x * wreg[i].x + xv.y * wreg[i].y + xv.z * wreg[i].z + xv.w * wreg[i].w;
    }
    s += acc; q = fmaf(acc, acc, q);
  }
  ps[h][c] = s; pq[h][c] = q;
  __syncthreads();
  if (t < 128) {
    bnp2[blockIdx.x * 256 + t]       = ps[0][t] + ps[1][t];
    bnp2[blockIdx.x * 256 + 128 + t] = pq[0][t] + pq[1][t];
  }
}

__global__ void bn2_final_kernel(const float* __restrict__ bnp2, const float* __restrict__ g2,
                                 const float* __restrict__ bt2, float* __restrict__ bn2s) {
  int c = threadIdx.x;  // 128
  float S = 0.f, Q = 0.f;
  for (int i = 0; i < 1024; ++i) { S += bnp2[i * 256 + c]; Q += bnp2[i * 256 + 128 + c]; }
  float m = S * (1.0f / 131072.0f);
  float var = Q * (1.0f / 131072.0f) - m * m;
  float sc = g2[c] * rsqrtf(var + EPSBN);
  bn2s[c] = sc;
  bn2s[128 + c] = bt2[c] - m * sc;
}

// ---------------- final: mlp2 + BN2 + ReLU + maxpool: 8192 blocks x 128 ----------------
__global__ __launch_bounds__(128) void final_kernel(const float* __restrict__ x2,
                                                    const float* __restrict__ w2,
                                                    const float* __restrict__ b2,
                                                    const float* __restrict__ bn2s,
                                                    float* __restrict__ out) {
  __shared__ float sx2[16 * 64];
  const int t = threadIdx.x;
  const float4* s4 = reinterpret_cast<const float4*>(x2 + (size_t)blockIdx.x * 1024);
  float4* d4 = reinterpret_cast<float4*>(sx2);
  for (int i = 0; i < 2; ++i) d4[i * 128 + t] = s4[i * 128 + t];
  __syncthreads();
  const int c = t;
  float4 wreg[16];
  const float4* w4 = reinterpret_cast<const float4*>(w2 + c * 64);
#pragma unroll
  for (int i = 0; i < 16; ++i) wreg[i] = w4[i];
  const float bb = b2[c], sc = bn2s[c], sh = bn2s[128 + c];
  float mx = -3.4e38f;
  for (int k = 0; k < 16; ++k) {
    const float4* xr = reinterpret_cast<const float4*>(&sx2[k * 64]);
    float acc = bb;
#pragma unroll
    for (int i = 0; i < 16; ++i) {
      float4 xv = xr[i];
      acc += xv.x * wreg[i].x + xv.y * wreg[i].y + xv.z * wreg[i].z + xv.w * wreg[i].w;
    }
    float y = fmaxf(0.f, acc * sc + sh);
    mx = fmaxf(mx, y);
  }
  out[24576 + (size_t)blockIdx.x * 128 + c] = mx;
}

// ---------------- launch ----------------
extern "C" void kernel_launch(void* const* d_in, const int* in_sizes, int n_in,
                              void* d_out, int out_size, void* d_ws, size_t ws_size,
                              hipStream_t stream) {
  const float* xyz  = (const float*)d_in[0];
  const float* feat = (const float*)d_in[1];
  const float* w1   = (const float*)d_in[2];
  const float* b1   = (const float*)d_in[3];
  const float* g1   = (const float*)d_in[4];
  const float* bt1  = (const float*)d_in[5];
  const float* fc1w = (const float*)d_in[6];
  const float* fc1b = (const float*)d_in[7];
  const float* wq   = (const float*)d_in[8];
  const float* wk   = (const float*)d_in[9];
  const float* wv   = (const float*)d_in[10];
  const float* fc2w = (const float*)d_in[11];
  const float* fc2b = (const float*)d_in[12];
  const float* w2   = (const float*)d_in[13];
  const float* b2   = (const float*)d_in[14];
  const float* g2   = (const float*)d_in[15];
  const float* bt2  = (const float*)d_in[16];
  float* out = (float*)d_out;
  char* ws = (char*)d_ws;

  int*    knn_idx = (int*)(ws + WS_KNN_IDX);
  float*  x1      = (float*)(ws + WS_X1);
  float*  bnp1    = (float*)(ws + WS_BNP1);
  float*  bn1s    = (float*)(ws + WS_BN1S);
  float*  bnp2    = (float*)(ws + WS_BNP2);
  float*  bn2s    = (float*)(ws + WS_BN2S);
  float*  Abuf    = (float*)(ws + WS_A);
  float*  Bbuf    = (float*)(ws + WS_B);
  float*  qb      = (float*)(ws + WS_QB);
  float*  kb      = (float*)(ws + WS_KB);
  float*  Wc      = (float*)(ws + WS_WC);
  float*  G       = (float*)(ws + WS_G);
  float*  ZT      = (float*)(ws + WS_ZT);
  float*  u       = (float*)(ws + WS_U);
  float*  w       = (float*)(ws + WS_W);
  float*  tb      = (float*)(ws + WS_TB);
  float*  cc      = (float*)(ws + WS_CC);
  float4* pts4    = (float4*)(ws + WS_PTS4);

  prep1_kernel<<<512, 256, 0, stream>>>(wq, wk, fc1w, fc1b, fc2w, wv, xyz,
                                        Abuf, Bbuf, qb, kb, Wc, pts4);
  prep2_kernel<<<34, 256, 0, stream>>>(Abuf, Bbuf, qb, kb, Wc, fc1w, fc1b, fc2b,
                                       G, u, w, cc, ZT, tb);

  fps_kernel<<<8, 256, 0, stream>>>(pts4, out);
  knn_kernel<<<2048, 256, 0, stream>>>(pts4, out, knn_idx);
  mlp1_kernel<<<512, 256, 0, stream>>>(feat, knn_idx, w1, b1, x1);
  bn1_stats_kernel<<<512, 256, 0, stream>>>(x1, bnp1);
  bn1_final_kernel<<<1, 64, 0, stream>>>(bnp1, g1, bt1, bn1s);
  transformer_fused<<<8192, 64, 0, stream>>>(x1, bn1s, G, u, w, cc, ZT, tb);
  bn2_stats_kernel<<<1024, 256, 0, stream>>>(x1, w2, b2, bnp2);
  bn2_final_kernel<<<1, 128, 0, stream>>>(bnp2, g2, bt2, bn2s);
  final_kernel<<<8192, 128, 0, stream>>>(x1, w2, b2, bn2s, out);
}

// Round 6
// 1367.145 us; speedup vs baseline: 8.9308x; 1.0079x over previous
//
#include <hip/hip_runtime.h>

// ---------------- sizes ----------------
// B=8, N=4096, S=1024, K=16, C1=64, D=512, C2=128
// positions P = 8*1024*16 = 131072
#define EPSBN 1e-5f
#define INVSQ 0.04419417382415922f  // 1/sqrt(512)

// ---------------- ws byte offsets ----------------
#define WS_KNN_IDX   32768u       // 131072*4          = 524288
#define WS_X1        1048576u     // 131072*64*4       = 33554432 (also holds x2 in-place)
#define WS_BNP1      34603008u    // 512*128*4         = 262144
#define WS_BN1S      34865152u    // 128*4             = 512
#define WS_BNP2      34865664u    // 1024*256*4        = 1048576
#define WS_BN2S      35914240u    // 256*4             = 1024
#define WS_A         35915264u    // 512*64*4          = 131072
#define WS_B         36046336u    // 512*64*4
#define WS_QB        36177408u    // 512*4
#define WS_KB        36179456u    // 512*4
#define WS_WC        36181504u    // 64*512*4          = 131072
#define WS_G         36312576u    // 64*64*4           = 16384
#define WS_ZT        36328960u    // 64*64*4
#define WS_U         36345344u    // 64*4
#define WS_W         36345600u
#define WS_TB        36345856u
#define WS_CC        36346112u    // 4
#define WS_PTS4      36346368u    // 32768*16          = 524288 (end ~36.9MB)

// ---------------- prep1: weight combines stage 1 + point packing ----------------
__global__ __launch_bounds__(256) void prep1_kernel(const float* __restrict__ wq,
                                                    const float* __restrict__ wk,
                                                    const float* __restrict__ fc1w,
                                                    const float* __restrict__ fc1b,
                                                    const float* __restrict__ fc2w,
                                                    const float* __restrict__ wv,
                                                    const float* __restrict__ xyz,
                                                    float* __restrict__ A, float* __restrict__ B,
                                                    float* __restrict__ qb, float* __restrict__ kb,
                                                    float* __restrict__ Wc,
                                                    float4* __restrict__ pts4) {
  const int blk = blockIdx.x;
  if (blk < 256) {
    int id = blk * 256 + threadIdx.x;  // 0..65535
    int which = id >> 15;
    int rem = id & 32767;
    int r = rem >> 6, i = rem & 63;
    const float* W = which ? wk : wq;
    float s = 0.f;
    for (int d = 0; d < 512; ++d) s = fmaf(W[r * 512 + d], fc1w[d * 64 + i], s);
    (which ? B : A)[r * 64 + i] = s;
    if (i == 0) {
      float sb = 0.f;
      for (int d = 0; d < 512; ++d) sb = fmaf(W[r * 512 + d], fc1b[d], sb);
      (which ? kb : qb)[r] = sb;
    }
  } else if (blk < 384) {
    int id = (blk - 256) * 256 + threadIdx.x;  // 0..32767
    int c = id >> 9, d = id & 511;
    float s = 0.f;
    for (int e = 0; e < 512; ++e) s = fmaf(fc2w[c * 512 + e], wv[e * 512 + d], s);
    Wc[c * 512 + d] = s;
  } else {
    int id = (blk - 384) * 256 + threadIdx.x;  // 0..32767
    float x = xyz[id * 3 + 0], y = xyz[id * 3 + 1], z = xyz[id * 3 + 2];
    float pp = __fadd_rn(__fadd_rn(__fmul_rn(x, x), __fmul_rn(y, y)), __fmul_rn(z, z));
    pts4[id] = make_float4(x, y, z, pp);
  }
}

// ---------------- prep2: weight combines stage 2 ----------------
__global__ __launch_bounds__(256) void prep2_kernel(const float* __restrict__ A,
                                                    const float* __restrict__ B,
                                                    const float* __restrict__ qb,
                                                    const float* __restrict__ kb,
                                                    const float* __restrict__ Wc,
                                                    const float* __restrict__ fc1w,
                                                    const float* __restrict__ fc1b,
                                                    const float* __restrict__ fc2b,
                                                    float* __restrict__ G, float* __restrict__ u,
                                                    float* __restrict__ w, float* __restrict__ cc,
                                                    float* __restrict__ ZT, float* __restrict__ tb) {
  const int blk = blockIdx.x;
  if (blk < 17) {
    int id = blk * 256 + threadIdx.x;
    if (id < 4096) {
      int i = id >> 6, j = id & 63;
      float s = 0.f;
      for (int d = 0; d < 512; ++d) s = fmaf(A[d * 64 + i], B[d * 64 + j], s);
      G[i * 64 + j] = s * INVSQ;
    } else if (id < 4160) {
      int i = id - 4096; float s = 0.f;
      for (int d = 0; d < 512; ++d) s = fmaf(A[d * 64 + i], kb[d], s);
      u[i] = s * INVSQ;
    } else if (id < 4224) {
      int j = id - 4160; float s = 0.f;
      for (int d = 0; d < 512; ++d) s = fmaf(B[d * 64 + j], qb[d], s);
      w[j] = s * INVSQ;
    } else if (id == 4224) {
      float s = 0.f;
      for (int d = 0; d < 512; ++d) s = fmaf(qb[d], kb[d], s);
      cc[0] = s * INVSQ;
    }
  } else {
    int id = (blk - 17) * 256 + threadIdx.x;
    if (id < 4096) {
      int i = id >> 6, c = id & 63;
      float s = 0.f;
      for (int d = 0; d < 512; ++d) s = fmaf(Wc[c * 512 + d], fc1w[d * 64 + i], s);
      ZT[i * 64 + c] = s;
    } else if (id < 4160) {
      int c = id - 4096; float s = 0.f;
      for (int d = 0; d < 512; ++d) s = fmaf(Wc[c * 512 + d], fc1b[d], s);
      tb[c] = s + fc2b[c];
    }
  }
}

// ---------------- FPS: 8 blocks x 512 threads, DPP wave-reduce on packed u64 ----------------
// key = (float_bits(dist) << 32) | (4095 - idx)  -> max key == max dist, min idx on ties
#define FPS_REDSTEP(CTRL)                                                              \
  {                                                                                    \
    unsigned lo2 = (unsigned)__builtin_amdgcn_update_dpp(0, (int)klo, CTRL, 0xF, 0xF, true); \
    unsigned hi2 = (unsigned)__builtin_amdgcn_update_dpp(0, (int)khi, CTRL, 0xF, 0xF, true); \
    bool tk = (hi2 > khi) || (hi2 == khi && lo2 > klo);                                \
    khi = tk ? hi2 : khi; klo = tk ? lo2 : klo;                                        \
  }

__global__ __launch_bounds__(512) void fps_kernel(const float4* __restrict__ pts4,
                                                  float* __restrict__ out_xyz) {
  __shared__ float4 spts[4096];                 // 64 KB
  __shared__ unsigned long long red[2][8];      // [parity][wave]
  const int b = blockIdx.x;
  const int t = threadIdx.x;
  const int lane = t & 63, wid = t >> 6;
  const float4* pb = pts4 + (size_t)b * 4096;
  float px[8], py[8], pz[8], pd[8];
#pragma unroll
  for (int i = 0; i < 8; ++i) {
    int j = i * 512 + t;
    float4 p = pb[j];
    spts[j] = p;
    px[i] = p.x; py[i] = p.y; pz[i] = p.z; pd[i] = 1e10f;
  }
  __syncthreads();
  float4 c4 = spts[0];
  for (int it = 0; it < 1024; ++it) {
    if (t == 0) {
      out_xyz[(size_t)(b * 1024 + it) * 3 + 0] = c4.x;
      out_xyz[(size_t)(b * 1024 + it) * 3 + 1] = c4.y;
      out_xyz[(size_t)(b * 1024 + it) * 3 + 2] = c4.z;
    }
    // distance update + in-lane argmax (first-max kept: ascending j within lane)
    float bv = -1.0f; int bj = 0;
#pragma unroll
    for (int i = 0; i < 8; ++i) {
      float dx = __fsub_rn(px[i], c4.x);
      float dy = __fsub_rn(py[i], c4.y);
      float dz = __fsub_rn(pz[i], c4.z);
      float d = __fadd_rn(__fadd_rn(__fmul_rn(dx, dx), __fmul_rn(dy, dy)), __fmul_rn(dz, dz));
      float nd = fminf(pd[i], d);
      pd[i] = nd;
      bool g = nd > bv;
      bv = g ? nd : bv;
      bj = g ? (i * 512 + t) : bj;
    }
    // pack key
    unsigned klo = 4095u - (unsigned)bj;
    unsigned khi = __float_as_uint(bv);
    // DPP wave64 max-reduce (VALU only); result lands in lane 63
    FPS_REDSTEP(0x111)  // row_shr:1
    FPS_REDSTEP(0x112)  // row_shr:2
    FPS_REDSTEP(0x114)  // row_shr:4
    FPS_REDSTEP(0x118)  // row_shr:8
    FPS_REDSTEP(0x142)  // row_bcast:15
    FPS_REDSTEP(0x143)  // row_bcast:31
    unsigned wlo = (unsigned)__builtin_amdgcn_readlane((int)klo, 63);
    unsigned whi = (unsigned)__builtin_amdgcn_readlane((int)khi, 63);
    const int p = it & 1;
    if (lane == 0) red[p][wid] = (((unsigned long long)whi) << 32) | wlo;
    __syncthreads();
    // cross-wave combine: ALL 8 wave keys via four b128 broadcast reads, tree select
    const ulonglong2* r2 = reinterpret_cast<const ulonglong2*>(&red[p][0]);
    ulonglong2 ka = r2[0];
    ulonglong2 kb = r2[1];
    ulonglong2 kc = r2[2];
    ulonglong2 kd = r2[3];
    unsigned long long m0 = (ka.x > ka.y) ? ka.x : ka.y;
    unsigned long long m1 = (kb.x > kb.y) ? kb.x : kb.y;
    unsigned long long m2 = (kc.x > kc.y) ? kc.x : kc.y;
    unsigned long long m3 = (kd.x > kd.y) ? kd.x : kd.y;
    unsigned long long ma = (m0 > m1) ? m0 : m1;
    unsigned long long mb = (m2 > m3) ? m2 : m3;
    unsigned long long k0 = (ma > mb) ? ma : mb;
    int jw = 4095 - (int)(unsigned)(k0 & 0xFFFFFFFFull);
    c4 = spts[jw];  // uniform broadcast read
  }
}

// ---------------- kNN: one wave per center, 2048 blocks x 256, no LDS ----------------
__global__ __launch_bounds__(256) void knn_kernel(const float4* __restrict__ pts4,
                                                  const float* __restrict__ new_xyz,
                                                  int* __restrict__ knn_idx) {
  const int t = threadIdx.x & 63;
  const int wave = (blockIdx.x << 2) | (threadIdx.x >> 6);  // center id 0..8191
  const int b = wave >> 10;
  const float4* P = pts4 + (size_t)b * 4096;
  const float cx = new_xyz[(size_t)wave * 3 + 0];
  const float cy = new_xyz[(size_t)wave * 3 + 1];
  const float cz = new_xyz[(size_t)wave * 3 + 2];
  const float cc = __fadd_rn(__fadd_rn(__fmul_rn(cx, cx), __fmul_rn(cy, cy)), __fmul_rn(cz, cz));
  float ldd[16]; int ldi[16];
#pragma unroll
  for (int q = 0; q < 16; ++q) { ldd[q] = 3.4e38f; ldi[q] = 0x7fffffff; }
  for (int i = 0; i < 64; ++i) {
    int j = i * 64 + t;  // coalesced across lanes
    float4 p = P[j];
    float dot = __fadd_rn(__fadd_rn(__fmul_rn(cx, p.x), __fmul_rn(cy, p.y)), __fmul_rn(cz, p.z));
    float d = __fsub_rn(__fadd_rn(cc, p.w), __fmul_rn(2.0f, dot));
    if (d < ldd[15] || (d == ldd[15] && j < ldi[15])) {
      float cd = d; int ci = j;
#pragma unroll
      for (int q = 0; q < 16; ++q) {
        bool sw = (cd < ldd[q]) || (cd == ldd[q] && ci < ldi[q]);
        float td = ldd[q]; int ti = ldi[q];
        if (sw) { ldd[q] = cd; ldi[q] = ci; cd = td; ci = ti; }
      }
    }
  }
  // 16-pop wave merge of 64 sorted lists
  float cd = ldd[0]; int ci = ldi[0];
  int* op = knn_idx + (size_t)wave * 16;
#pragma unroll 1
  for (int k = 0; k < 16; ++k) {
    float wd = cd; int wi = ci;
#pragma unroll
    for (int off = 1; off < 64; off <<= 1) {
      float ov = __shfl_xor(wd, off);
      int   oi = __shfl_xor(wi, off);
      bool tk = (ov < wd) || (ov == wd && oi < wi);
      wd = tk ? ov : wd; wi = tk ? oi : wi;
    }
    if (t == 0) op[k] = wi;
    if (wd == cd && wi == ci) {  // this lane's head was popped
#pragma unroll
      for (int q = 0; q < 15; ++q) { ldd[q] = ldd[q + 1]; ldi[q] = ldi[q + 1]; }
      ldd[15] = 3.4e38f; ldi[15] = 0x7fffffff;
    }
    cd = ldd[0]; ci = ldi[0];
  }
}

// ---------------- gather + mlp1: 512 blocks x 256 threads ----------------
__global__ __launch_bounds__(256) void mlp1_kernel(const float* __restrict__ feat,
                                                   const int* __restrict__ knn_idx,
                                                   const float* __restrict__ w1,
                                                   const float* __restrict__ b1,
                                                   float* __restrict__ x1) {
  __shared__ float w1s[64 * 64];
  __shared__ float b1s[64];
  const int t = threadIdx.x;
  for (int i = t; i < 4096; i += 256) w1s[i] = w1[i];
  if (t < 64) b1s[t] = b1[t];
  __syncthreads();
  const int pos = blockIdx.x * 256 + t;
  const int b = pos >> 14;
  const int n = knn_idx[pos];
  const float4* fp = reinterpret_cast<const float4*>(feat + ((size_t)(b * 4096 + n)) * 64);
  float4 fr[16];
#pragma unroll
  for (int i = 0; i < 16; ++i) fr[i] = fp[i];
  float4* op = reinterpret_cast<float4*>(x1 + (size_t)pos * 64);
#pragma unroll
  for (int cq = 0; cq < 16; ++cq) {
    float a0 = b1s[cq * 4 + 0], a1 = b1s[cq * 4 + 1], a2 = b1s[cq * 4 + 2], a3 = b1s[cq * 4 + 3];
#pragma unroll
    for (int iq = 0; iq < 16; ++iq) {
      float4 f4 = fr[iq];
      float4 wa = *reinterpret_cast<const float4*>(&w1s[(cq * 4 + 0) * 64 + iq * 4]);
      float4 wb = *reinterpret_cast<const float4*>(&w1s[(cq * 4 + 1) * 64 + iq * 4]);
      float4 wc = *reinterpret_cast<const float4*>(&w1s[(cq * 4 + 2) * 64 + iq * 4]);
      float4 wd = *reinterpret_cast<const float4*>(&w1s[(cq * 4 + 3) * 64 + iq * 4]);
      a0 += f4.x * wa.x + f4.y * wa.y + f4.z * wa.z + f4.w * wa.w;
      a1 += f4.x * wb.x + f4.y * wb.y + f4.z * wb.z + f4.w * wb.w;
      a2 += f4.x * wc.x + f4.y * wc.y + f4.z * wc.z + f4.w * wc.w;
      a3 += f4.x * wd.x + f4.y * wd.y + f4.z * wd.z + f4.w * wd.w;
    }
    op[cq] = make_float4(a0, a1, a2, a3);
  }
}

// ---------------- BN1 stats: 512 blocks x 256 ----------------
__global__ __launch_bounds__(256) void bn1_stats_kernel(const float* __restrict__ x1,
                                                        float* __restrict__ bnp1) {
  __shared__ float ls[4][64], lq[4][64];
  const int t = threadIdx.x, c = t & 63, g = t >> 6;
  const float* p = x1 + ((size_t)blockIdx.x * 256 + g * 64) * 64 + c;
  float s = 0.f, s2 = 0.f;
  for (int i = 0; i < 64; ++i) { float v = p[(size_t)i * 64]; s += v; s2 = fmaf(v, v, s2); }
  ls[g][c] = s; lq[g][c] = s2;
  __syncthreads();
  if (t < 64) {
    bnp1[blockIdx.x * 128 + t]      = ls[0][t] + ls[1][t] + ls[2][t] + ls[3][t];
    bnp1[blockIdx.x * 128 + 64 + t] = lq[0][t] + lq[1][t] + lq[2][t] + lq[3][t];
  }
}

// parallelized: 1 block x 256 (c = t&63, g = t>>6 handles 128 partials)
__global__ __launch_bounds__(256) void bn1_final_kernel(const float* __restrict__ bnp1,
                                                        const float* __restrict__ g1,
                                                        const float* __restrict__ bt1,
                                                        float* __restrict__ bn1s) {
  __shared__ float rs[4][64], rq[4][64];
  const int t = threadIdx.x, c = t & 63, g = t >> 6;
  float S = 0.f, Q = 0.f;
  for (int i = g * 128; i < g * 128 + 128; ++i) {
    S += bnp1[i * 128 + c];
    Q += bnp1[i * 128 + 64 + c];
  }
  rs[g][c] = S; rq[g][c] = Q;
  __syncthreads();
  if (t < 64) {
    float Sa = rs[0][t] + rs[1][t] + rs[2][t] + rs[3][t];
    float Qa = rq[0][t] + rq[1][t] + rq[2][t] + rq[3][t];
    float m = Sa * (1.0f / 131072.0f);
    float var = Qa * (1.0f / 131072.0f) - m * m;
    float sc = g1[t] * rsqrtf(var + EPSBN);
    bn1s[t] = sc;
    bn1s[64 + t] = bt1[t] - m * sc;
  }
}

// ---------------- fused transformer (rank-64 collapsed): 8192 blocks x 64 ----------------
__global__ __launch_bounds__(64) void transformer_fused(
    float* __restrict__ x1, const float* __restrict__ bn1s,
    const float* __restrict__ G, const float* __restrict__ u, const float* __restrict__ w,
    const float* __restrict__ cc, const float* __restrict__ ZT, const float* __restrict__ tb) {
  __shared__ float pre[16][65];
  __shared__ float ts[16][65];
  __shared__ float ys[16][65];
  __shared__ float ss[16][17];
  __shared__ float spu[16], spw[16];
  const int c = threadIdx.x;
  const size_t base = (size_t)blockIdx.x * 1024;
  const float sc = bn1s[c], sh = bn1s[64 + c];
  float pc[16];
#pragma unroll
  for (int k = 0; k < 16; ++k) {
    float v = x1[base + k * 64 + c];
    float p = fmaxf(0.f, v * sc + sh);
    pc[k] = p; pre[k][c] = p;
  }
  __syncthreads();
  float tcol[16], ycol[16];
#pragma unroll
  for (int k = 0; k < 16; ++k) { tcol[k] = 0.f; ycol[k] = 0.f; }
  for (int i = 0; i < 64; ++i) {
    float g = G[i * 64 + c];
    float z = ZT[i * 64 + c];
#pragma unroll
    for (int k = 0; k < 16; ++k) {
      float p = pre[k][i];
      tcol[k] = fmaf(p, g, tcol[k]);
      ycol[k] = fmaf(p, z, ycol[k]);
    }
  }
#pragma unroll
  for (int k = 0; k < 16; ++k) { ts[k][c] = tcol[k]; ys[k][c] = ycol[k]; }
  if (c < 16) {
    float s = 0.f;
    for (int i = 0; i < 64; ++i) s = fmaf(pre[c][i], u[i], s);
    spu[c] = s;
  } else if (c < 32) {
    int m = c - 16; float s = 0.f;
    for (int i = 0; i < 64; ++i) s = fmaf(pre[m][i], w[i], s);
    spw[m] = s;
  }
  __syncthreads();
  {
    const float cval = cc[0];
    const int m = c & 15, nb = c >> 4;
#pragma unroll
    for (int ng = 0; ng < 4; ++ng) {
      int n = ng * 4 + nb;
      float s = 0.f;
      for (int i = 0; i < 64; ++i) s = fmaf(ts[n][i], pre[m][i], s);
      ss[n][m] = s + spu[n] + spw[m] + cval;
    }
  }
  __syncthreads();
  if (c < 16) {
    float mx = -3.4e38f;
#pragma unroll
    for (int m = 0; m < 16; ++m) mx = fmaxf(mx, ss[c][m]);
    float e[16], sum = 0.f;
#pragma unroll
    for (int m = 0; m < 16; ++m) { e[m] = expf(ss[c][m] - mx); sum += e[m]; }
    float r = 1.0f / sum;
#pragma unroll
    for (int m = 0; m < 16; ++m) ss[c][m] = e[m] * r;
  }
  __syncthreads();
  const float tbc = tb[c];
  float o[16];
#pragma unroll
  for (int k = 0; k < 16; ++k) o[k] = 0.f;
#pragma unroll
  for (int m = 0; m < 16; ++m) {
    float yv = ys[m][c];
#pragma unroll
    for (int k = 0; k < 16; ++k) o[k] = fmaf(ss[k][m], yv, o[k]);
  }
#pragma unroll
  for (int k = 0; k < 16; ++k) x1[base + k * 64 + c] = o[k] + tbc + pc[k];
}

// ---------------- BN2 stats (computes mlp2 on the fly): 1024 blocks x 256 ----------------
__global__ __launch_bounds__(256) void bn2_stats_kernel(const float* __restrict__ x2,
                                                        const float* __restrict__ w2,
                                                        const float* __restrict__ b2,
                                                        float* __restrict__ bnp2) {
  __shared__ float sx2[128 * 64];
  __shared__ float ps[2][128], pq[2][128];
  const int t = threadIdx.x;
  const float4* s4 = reinterpret_cast<const float4*>(x2 + (size_t)blockIdx.x * 128 * 64);
  float4* d4 = reinterpret_cast<float4*>(sx2);
  for (int i = 0; i < 8; ++i) d4[i * 256 + t] = s4[i * 256 + t];
  __syncthreads();
  const int c = t & 127, h = t >> 7;
  float4 wreg[16];
  const float4* w4 = reinterpret_cast<const float4*>(w2 + c * 64);
#pragma unroll
  for (int i = 0; i < 16; ++i) wreg[i] = w4[i];
  const float bb = b2[c];
  float s = 0.f, q = 0.f;
  for (int p = 0; p < 64; ++p) {
    const float4* xr = reinterpret_cast<const float4*>(&sx2[(h * 64 + p) * 64]);
    float acc = bb;
#pragma unroll
    for (int i = 0; i < 16; ++i) {
      float4 xv = xr[i];
      acc += xv.x * wreg[i].x + xv.y * wreg[i].y + xv.z * wreg[i].z + xv.w * wreg[i].w;
    }
    s += acc; q = fmaf(acc, acc, q);
  }
  ps[h][c] = s; pq[h][c] = q;
  __syncthreads();
  if (t < 128) {
    bnp2[blockIdx.x * 256 + t]       = ps[0][t] + ps[1][t];
    bnp2[blockIdx.x * 256 + 128 + t] = pq[0][t] + pq[1][t];
  }
}

// parallelized: 1 block x 512 (c = t&127, g = t>>7 handles 256 partials)
__global__ __launch_bounds__(512) void bn2_final_kernel(const float* __restrict__ bnp2,
                                                        const float* __restrict__ g2,
                                                        const float* __restrict__ bt2,
                                                        float* __restrict__ bn2s) {
  __shared__ float rs[4][128], rq[4][128];
  const int t = threadIdx.x, c = t & 127, g = t >> 7;
  float S = 0.f, Q = 0.f;
  for (int i = g * 256; i < g * 256 + 256; ++i) {
    S += bnp2[i * 256 + c];
    Q += bnp2[i * 256 + 128 + c];
  }
  rs[g][c] = S; rq[g][c] = Q;
  __syncthreads();
  if (t < 128) {
    float Sa = rs[0][t] + rs[1][t] + rs[2][t] + rs[3][t];
    float Qa = rq[0][t] + rq[1][t] + rq[2][t] + rq[3][t];
    float m = Sa * (1.0f / 131072.0f);
    float var = Qa * (1.0f / 131072.0f) - m * m;
    float sc = g2[t] * rsqrtf(var + EPSBN);
    bn2s[t] = sc;
    bn2s[128 + t] = bt2[t] - m * sc;
  }
}

// ---------------- final: mlp2 + BN2 + ReLU + maxpool: 8192 blocks x 128 ----------------
__global__ __launch_bounds__(128) void final_kernel(const float* __restrict__ x2,
                                                    const float* __restrict__ w2,
                                                    const float* __restrict__ b2,
                                                    const float* __restrict__ bn2s,
                                                    float* __restrict__ out) {
  __shared__ float sx2[16 * 64];
  const int t = threadIdx.x;
  const float4* s4 = reinterpret_cast<const float4*>(x2 + (size_t)blockIdx.x * 1024);
  float4* d4 = reinterpret_cast<float4*>(sx2);
  for (int i = 0; i < 2; ++i) d4[i * 128 + t] = s4[i * 128 + t];
  __syncthreads();
  const int c = t;
  float4 wreg[16];
  const float4* w4 = reinterpret_cast<const float4*>(w2 + c * 64);
#pragma unroll
  for (int i = 0; i < 16; ++i) wreg[i] = w4[i];
  const float bb = b2[c], sc = bn2s[c], sh = bn2s[128 + c];
  float mx = -3.4e38f;
  for (int k = 0; k < 16; ++k) {
    const float4* xr = reinterpret_cast<const float4*>(&sx2[k * 64]);
    float acc = bb;
#pragma unroll
    for (int i = 0; i < 16; ++i) {
      float4 xv = xr[i];
      acc += xv.x * wreg[i].x + xv.y * wreg[i].y + xv.z * wreg[i].z + xv.w * wreg[i].w;
    }
    float y = fmaxf(0.f, acc * sc + sh);
    mx = fmaxf(mx, y);
  }
  out[24576 + (size_t)blockIdx.x * 128 + c] = mx;
}

// ---------------- launch ----------------
extern "C" void kernel_launch(void* const* d_in, const int* in_sizes, int n_in,
                              void* d_out, int out_size, void* d_ws, size_t ws_size,
                              hipStream_t stream) {
  const float* xyz  = (const float*)d_in[0];
  const float* feat = (const float*)d_in[1];
  const float* w1   = (const float*)d_in[2];
  const float* b1   = (const float*)d_in[3];
  const float* g1   = (const float*)d_in[4];
  const float* bt1  = (const float*)d_in[5];
  const float* fc1w = (const float*)d_in[6];
  const float* fc1b = (const float*)d_in[7];
  const float* wq   = (const float*)d_in[8];
  const float* wk   = (const float*)d_in[9];
  const float* wv   = (const float*)d_in[10];
  const float* fc2w = (const float*)d_in[11];
  const float* fc2b = (const float*)d_in[12];
  const float* w2   = (const float*)d_in[13];
  const float* b2   = (const float*)d_in[14];
  const float* g2   = (const float*)d_in[15];
  const float* bt2  = (const float*)d_in[16];
  float* out = (float*)d_out;
  char* ws = (char*)d_ws;

  int*    knn_idx = (int*)(ws + WS_KNN_IDX);
  float*  x1      = (float*)(ws + WS_X1);
  float*  bnp1    = (float*)(ws + WS_BNP1);
  float*  bn1s    = (float*)(ws + WS_BN1S);
  float*  bnp2    = (float*)(ws + WS_BNP2);
  float*  bn2s    = (float*)(ws + WS_BN2S);
  float*  Abuf    = (float*)(ws + WS_A);
  float*  Bbuf    = (float*)(ws + WS_B);
  float*  qb      = (float*)(ws + WS_QB);
  float*  kb      = (float*)(ws + WS_KB);
  float*  Wc      = (float*)(ws + WS_WC);
  float*  G       = (float*)(ws + WS_G);
  float*  ZT      = (float*)(ws + WS_ZT);
  float*  u       = (float*)(ws + WS_U);
  float*  w       = (float*)(ws + WS_W);
  float*  tb      = (float*)(ws + WS_TB);
  float*  cc      = (float*)(ws + WS_CC);
  float4* pts4    = (float4*)(ws + WS_PTS4);

  prep1_kernel<<<512, 256, 0, stream>>>(wq, wk, fc1w, fc1b, fc2w, wv, xyz,
                                        Abuf, Bbuf, qb, kb, Wc, pts4);
  prep2_kernel<<<34, 256, 0, stream>>>(Abuf, Bbuf, qb, kb, Wc, fc1w, fc1b, fc2b,
                                       G, u, w, cc, ZT, tb);

  fps_kernel<<<8, 512, 0, stream>>>(pts4, out);
  knn_kernel<<<2048, 256, 0, stream>>>(pts4, out, knn_idx);
  mlp1_kernel<<<512, 256, 0, stream>>>(feat, knn_idx, w1, b1, x1);
  bn1_stats_kernel<<<512, 256, 0, stream>>>(x1, bnp1);
  bn1_final_kernel<<<1, 256, 0, stream>>>(bnp1, g1, bt1, bn1s);
  transformer_fused<<<8192, 64, 0, stream>>>(x1, bn1s, G, u, w, cc, ZT, tb);
  bn2_stats_kernel<<<1024, 256, 0, stream>>>(x1, w2, b2, bnp2);
  bn2_final_kernel<<<1, 512, 0, stream>>>(bnp2, g2, bt2, bn2s);
  final_kernel<<<8192, 128, 0, stream>>>(x1, w2, b2, bn2s, out);
}

// Round 7
// 1322.885 us; speedup vs baseline: 9.2296x; 1.0335x over previous
//
#include <hip/hip_runtime.h>

// ---------------- sizes ----------------
// B=8, N=4096, S=1024, K=16, C1=64, D=512, C2=128
// positions P = 8*1024*16 = 131072
#define EPSBN 1e-5f
#define INVSQ 0.04419417382415922f  // 1/sqrt(512)

// ---------------- ws byte offsets ----------------
#define WS_KNN_IDX   32768u       // 131072*4          = 524288
#define WS_X1        1048576u     // 131072*64*4       = 33554432 (also holds x2 in-place)
#define WS_BNP1      34603008u    // 512*128*4         = 262144
#define WS_BN1S      34865152u    // 128*4             = 512
#define WS_BNP2      34865664u    // 1024*256*4        = 1048576
#define WS_BN2S      35914240u    // 256*4             = 1024
#define WS_A         35915264u    // 512*64*4          = 131072
#define WS_B         36046336u    // 512*64*4
#define WS_QB        36177408u    // 512*4
#define WS_KB        36179456u    // 512*4
#define WS_WC        36181504u    // 64*512*4          = 131072
#define WS_G         36312576u    // 64*64*4           = 16384
#define WS_ZT        36328960u    // 64*64*4
#define WS_U         36345344u    // 64*4
#define WS_W         36345600u
#define WS_TB        36345856u
#define WS_CC        36346112u    // 4
#define WS_PTS4      36346368u    // 32768*16          = 524288 (end ~36.9MB)

// ---------------- prep1: weight combines stage 1 + point packing ----------------
__global__ __launch_bounds__(256) void prep1_kernel(const float* __restrict__ wq,
                                                    const float* __restrict__ wk,
                                                    const float* __restrict__ fc1w,
                                                    const float* __restrict__ fc1b,
                                                    const float* __restrict__ fc2w,
                                                    const float* __restrict__ wv,
                                                    const float* __restrict__ xyz,
                                                    float* __restrict__ A, float* __restrict__ B,
                                                    float* __restrict__ qb, float* __restrict__ kb,
                                                    float* __restrict__ Wc,
                                                    float4* __restrict__ pts4) {
  const int blk = blockIdx.x;
  if (blk < 256) {
    int id = blk * 256 + threadIdx.x;  // 0..65535
    int which = id >> 15;
    int rem = id & 32767;
    int r = rem >> 6, i = rem & 63;
    const float* W = which ? wk : wq;
    float s = 0.f;
    for (int d = 0; d < 512; ++d) s = fmaf(W[r * 512 + d], fc1w[d * 64 + i], s);
    (which ? B : A)[r * 64 + i] = s;
    if (i == 0) {
      float sb = 0.f;
      for (int d = 0; d < 512; ++d) sb = fmaf(W[r * 512 + d], fc1b[d], sb);
      (which ? kb : qb)[r] = sb;
    }
  } else if (blk < 384) {
    int id = (blk - 256) * 256 + threadIdx.x;  // 0..32767
    int c = id >> 9, d = id & 511;
    float s = 0.f;
    for (int e = 0; e < 512; ++e) s = fmaf(fc2w[c * 512 + e], wv[e * 512 + d], s);
    Wc[c * 512 + d] = s;
  } else {
    int id = (blk - 384) * 256 + threadIdx.x;  // 0..32767
    float x = xyz[id * 3 + 0], y = xyz[id * 3 + 1], z = xyz[id * 3 + 2];
    float pp = __fadd_rn(__fadd_rn(__fmul_rn(x, x), __fmul_rn(y, y)), __fmul_rn(z, z));
    pts4[id] = make_float4(x, y, z, pp);
  }
}

// ---------------- prep2: weight combines stage 2 ----------------
__global__ __launch_bounds__(256) void prep2_kernel(const float* __restrict__ A,
                                                    const float* __restrict__ B,
                                                    const float* __restrict__ qb,
                                                    const float* __restrict__ kb,
                                                    const float* __restrict__ Wc,
                                                    const float* __restrict__ fc1w,
                                                    const float* __restrict__ fc1b,
                                                    const float* __restrict__ fc2b,
                                                    float* __restrict__ G, float* __restrict__ u,
                                                    float* __restrict__ w, float* __restrict__ cc,
                                                    float* __restrict__ ZT, float* __restrict__ tb) {
  const int blk = blockIdx.x;
  if (blk < 17) {
    int id = blk * 256 + threadIdx.x;
    if (id < 4096) {
      int i = id >> 6, j = id & 63;
      float s = 0.f;
      for (int d = 0; d < 512; ++d) s = fmaf(A[d * 64 + i], B[d * 64 + j], s);
      G[i * 64 + j] = s * INVSQ;
    } else if (id < 4160) {
      int i = id - 4096; float s = 0.f;
      for (int d = 0; d < 512; ++d) s = fmaf(A[d * 64 + i], kb[d], s);
      u[i] = s * INVSQ;
    } else if (id < 4224) {
      int j = id - 4160; float s = 0.f;
      for (int d = 0; d < 512; ++d) s = fmaf(B[d * 64 + j], qb[d], s);
      w[j] = s * INVSQ;
    } else if (id == 4224) {
      float s = 0.f;
      for (int d = 0; d < 512; ++d) s = fmaf(qb[d], kb[d], s);
      cc[0] = s * INVSQ;
    }
  } else {
    int id = (blk - 17) * 256 + threadIdx.x;
    if (id < 4096) {
      int i = id >> 6, c = id & 63;
      float s = 0.f;
      for (int d = 0; d < 512; ++d) s = fmaf(Wc[c * 512 + d], fc1w[d * 64 + i], s);
      ZT[i * 64 + c] = s;
    } else if (id < 4160) {
      int c = id - 4096; float s = 0.f;
      for (int d = 0; d < 512; ++d) s = fmaf(Wc[c * 512 + d], fc1b[d], s);
      tb[c] = s + fc2b[c];
    }
  }
}

// ---------------- FPS: 8 blocks x 256 threads, DPP wave-reduce, LDS-buffered centers ----------------
// key = (float_bits(dist) << 32) | (4095 - idx)  -> max key == max dist, min idx on ties
// Centers buffered in LDS so the main loop issues NO global stores (the
// __syncthreads-implied vmcnt(0) drain was stalling every iteration).
#define FPS_REDSTEP(CTRL)                                                              \
  {                                                                                    \
    unsigned lo2 = (unsigned)__builtin_amdgcn_update_dpp(0, (int)klo, CTRL, 0xF, 0xF, true); \
    unsigned hi2 = (unsigned)__builtin_amdgcn_update_dpp(0, (int)khi, CTRL, 0xF, 0xF, true); \
    bool tk = (hi2 > khi) || (hi2 == khi && lo2 > klo);                                \
    khi = tk ? hi2 : khi; klo = tk ? lo2 : klo;                                        \
  }

__global__ __launch_bounds__(256) void fps_kernel(const float4* __restrict__ pts4,
                                                  float* __restrict__ out_xyz) {
  __shared__ float4 spts[4096];                 // 64 KB
  __shared__ float4 cent4[1024];                // 16 KB center buffer
  __shared__ unsigned long long red[2][4];      // [parity][wave]
  const int b = blockIdx.x;
  const int t = threadIdx.x;
  const int lane = t & 63, wid = t >> 6;
  const float4* pb = pts4 + (size_t)b * 4096;
  float px[16], py[16], pz[16], pd[16];
#pragma unroll
  for (int i = 0; i < 16; ++i) {
    int j = i * 256 + t;
    float4 p = pb[j];
    spts[j] = p;
    px[i] = p.x; py[i] = p.y; pz[i] = p.z; pd[i] = 1e10f;
  }
  __syncthreads();
  float4 c4 = spts[0];
  for (int it = 0; it < 1024; ++it) {
    if (t == 0) cent4[it] = c4;  // LDS only: cheap lgkm drain at barrier
    // distance update + in-lane argmax (first-max kept: ascending j within lane)
    float bv = -1.0f; int bj = 0;
#pragma unroll
    for (int i = 0; i < 16; ++i) {
      float dx = __fsub_rn(px[i], c4.x);
      float dy = __fsub_rn(py[i], c4.y);
      float dz = __fsub_rn(pz[i], c4.z);
      float d = __fadd_rn(__fadd_rn(__fmul_rn(dx, dx), __fmul_rn(dy, dy)), __fmul_rn(dz, dz));
      float nd = fminf(pd[i], d);
      pd[i] = nd;
      bool g = nd > bv;
      bv = g ? nd : bv;
      bj = g ? (i * 256 + t) : bj;
    }
    // pack key
    unsigned klo = 4095u - (unsigned)bj;
    unsigned khi = __float_as_uint(bv);
    // DPP wave64 max-reduce (VALU only); result lands in lane 63
    FPS_REDSTEP(0x111)  // row_shr:1
    FPS_REDSTEP(0x112)  // row_shr:2
    FPS_REDSTEP(0x114)  // row_shr:4
    FPS_REDSTEP(0x118)  // row_shr:8
    FPS_REDSTEP(0x142)  // row_bcast:15
    FPS_REDSTEP(0x143)  // row_bcast:31
    unsigned wlo = (unsigned)__builtin_amdgcn_readlane((int)klo, 63);
    unsigned whi = (unsigned)__builtin_amdgcn_readlane((int)khi, 63);
    const int par = it & 1;
    if (lane == 0) red[par][wid] = (((unsigned long long)whi) << 32) | wlo;
    __syncthreads();
    // cross-wave combine: ALL 4 wave keys via two b128 broadcast reads, tree select
    const ulonglong2* r2 = reinterpret_cast<const ulonglong2*>(&red[par][0]);
    ulonglong2 ka = r2[0];
    ulonglong2 kb = r2[1];
    unsigned long long m0 = (ka.x > ka.y) ? ka.x : ka.y;
    unsigned long long m1 = (kb.x > kb.y) ? kb.x : kb.y;
    unsigned long long k0 = (m0 > m1) ? m0 : m1;
    int jw = 4095 - (int)(unsigned)(k0 & 0xFFFFFFFFull);
    c4 = spts[jw];  // uniform broadcast read
  }
  __syncthreads();
  // bulk coalesced copy-out of centers: 1024 x (x,y,z)
  for (int o = t; o < 3072; o += 256) {
    int j = o / 3;
    int c = o - 3 * j;
    out_xyz[(size_t)b * 3072 + o] = (&cent4[j].x)[c];
  }
}

// ---------------- kNN: one wave per center, 2048 blocks x 256, no LDS ----------------
__global__ __launch_bounds__(256) void knn_kernel(const float4* __restrict__ pts4,
                                                  const float* __restrict__ new_xyz,
                                                  int* __restrict__ knn_idx) {
  const int t = threadIdx.x & 63;
  const int wave = (blockIdx.x << 2) | (threadIdx.x >> 6);  // center id 0..8191
  const int b = wave >> 10;
  const float4* P = pts4 + (size_t)b * 4096;
  const float cx = new_xyz[(size_t)wave * 3 + 0];
  const float cy = new_xyz[(size_t)wave * 3 + 1];
  const float cz = new_xyz[(size_t)wave * 3 + 2];
  const float cc = __fadd_rn(__fadd_rn(__fmul_rn(cx, cx), __fmul_rn(cy, cy)), __fmul_rn(cz, cz));
  float ldd[16]; int ldi[16];
#pragma unroll
  for (int q = 0; q < 16; ++q) { ldd[q] = 3.4e38f; ldi[q] = 0x7fffffff; }
  for (int i = 0; i < 64; ++i) {
    int j = i * 64 + t;  // coalesced across lanes
    float4 p = P[j];
    float dot = __fadd_rn(__fadd_rn(__fmul_rn(cx, p.x), __fmul_rn(cy, p.y)), __fmul_rn(cz, p.z));
    float d = __fsub_rn(__fadd_rn(cc, p.w), __fmul_rn(2.0f, dot));
    if (d < ldd[15] || (d == ldd[15] && j < ldi[15])) {
      float cd = d; int ci = j;
#pragma unroll
      for (int q = 0; q < 16; ++q) {
        bool sw = (cd < ldd[q]) || (cd == ldd[q] && ci < ldi[q]);
        float td = ldd[q]; int ti = ldi[q];
        if (sw) { ldd[q] = cd; ldi[q] = ci; cd = td; ci = ti; }
      }
    }
  }
  // 16-pop wave merge of 64 sorted lists
  float cd = ldd[0]; int ci = ldi[0];
  int* op = knn_idx + (size_t)wave * 16;
#pragma unroll 1
  for (int k = 0; k < 16; ++k) {
    float wd = cd; int wi = ci;
#pragma unroll
    for (int off = 1; off < 64; off <<= 1) {
      float ov = __shfl_xor(wd, off);
      int   oi = __shfl_xor(wi, off);
      bool tk = (ov < wd) || (ov == wd && oi < wi);
      wd = tk ? ov : wd; wi = tk ? oi : wi;
    }
    if (t == 0) op[k] = wi;
    if (wd == cd && wi == ci) {  // this lane's head was popped
#pragma unroll
      for (int q = 0; q < 15; ++q) { ldd[q] = ldd[q + 1]; ldi[q] = ldi[q + 1]; }
      ldd[15] = 3.4e38f; ldi[15] = 0x7fffffff;
    }
    cd = ldd[0]; ci = ldi[0];
  }
}

// ---------------- gather + mlp1: 512 blocks x 256 threads ----------------
__global__ __launch_bounds__(256) void mlp1_kernel(const float* __restrict__ feat,
                                                   const int* __restrict__ knn_idx,
                                                   const float* __restrict__ w1,
                                                   const float* __restrict__ b1,
                                                   float* __restrict__ x1) {
  __shared__ float w1s[64 * 64];
  __shared__ float b1s[64];
  const int t = threadIdx.x;
  for (int i = t; i < 4096; i += 256) w1s[i] = w1[i];
  if (t < 64) b1s[t] = b1[t];
  __syncthreads();
  const int pos = blockIdx.x * 256 + t;
  const int b = pos >> 14;
  const int n = knn_idx[pos];
  const float4* fp = reinterpret_cast<const float4*>(feat + ((size_t)(b * 4096 + n)) * 64);
  float4 fr[16];
#pragma unroll
  for (int i = 0; i < 16; ++i) fr[i] = fp[i];
  float4* op = reinterpret_cast<float4*>(x1 + (size_t)pos * 64);
#pragma unroll
  for (int cq = 0; cq < 16; ++cq) {
    float a0 = b1s[cq * 4 + 0], a1 = b1s[cq * 4 + 1], a2 = b1s[cq * 4 + 2], a3 = b1s[cq * 4 + 3];
#pragma unroll
    for (int iq = 0; iq < 16; ++iq) {
      float4 f4 = fr[iq];
      float4 wa = *reinterpret_cast<const float4*>(&w1s[(cq * 4 + 0) * 64 + iq * 4]);
      float4 wb = *reinterpret_cast<const float4*>(&w1s[(cq * 4 + 1) * 64 + iq * 4]);
      float4 wc = *reinterpret_cast<const float4*>(&w1s[(cq * 4 + 2) * 64 + iq * 4]);
      float4 wd = *reinterpret_cast<const float4*>(&w1s[(cq * 4 + 3) * 64 + iq * 4]);
      a0 += f4.x * wa.x + f4.y * wa.y + f4.z * wa.z + f4.w * wa.w;
      a1 += f4.x * wb.x + f4.y * wb.y + f4.z * wb.z + f4.w * wb.w;
      a2 += f4.x * wc.x + f4.y * wc.y + f4.z * wc.z + f4.w * wc.w;
      a3 += f4.x * wd.x + f4.y * wd.y + f4.z * wd.z + f4.w * wd.w;
    }
    op[cq] = make_float4(a0, a1, a2, a3);
  }
}

// ---------------- BN1 stats: 512 blocks x 256 ----------------
__global__ __launch_bounds__(256) void bn1_stats_kernel(const float* __restrict__ x1,
                                                        float* __restrict__ bnp1) {
  __shared__ float ls[4][64], lq[4][64];
  const int t = threadIdx.x, c = t & 63, g = t >> 6;
  const float* p = x1 + ((size_t)blockIdx.x * 256 + g * 64) * 64 + c;
  float s = 0.f, s2 = 0.f;
  for (int i = 0; i < 64; ++i) { float v = p[(size_t)i * 64]; s += v; s2 = fmaf(v, v, s2); }
  ls[g][c] = s; lq[g][c] = s2;
  __syncthreads();
  if (t < 64) {
    bnp1[blockIdx.x * 128 + t]      = ls[0][t] + ls[1][t] + ls[2][t] + ls[3][t];
    bnp1[blockIdx.x * 128 + 64 + t] = lq[0][t] + lq[1][t] + lq[2][t] + lq[3][t];
  }
}

// parallelized: 1 block x 256 (c = t&63, g = t>>6 handles 128 partials)
__global__ __launch_bounds__(256) void bn1_final_kernel(const float* __restrict__ bnp1,
                                                        const float* __restrict__ g1,
                                                        const float* __restrict__ bt1,
                                                        float* __restrict__ bn1s) {
  __shared__ float rs[4][64], rq[4][64];
  const int t = threadIdx.x, c = t & 63, g = t >> 6;
  float S = 0.f, Q = 0.f;
  for (int i = g * 128; i < g * 128 + 128; ++i) {
    S += bnp1[i * 128 + c];
    Q += bnp1[i * 128 + 64 + c];
  }
  rs[g][c] = S; rq[g][c] = Q;
  __syncthreads();
  if (t < 64) {
    float Sa = rs[0][t] + rs[1][t] + rs[2][t] + rs[3][t];
    float Qa = rq[0][t] + rq[1][t] + rq[2][t] + rq[3][t];
    float m = Sa * (1.0f / 131072.0f);
    float var = Qa * (1.0f / 131072.0f) - m * m;
    float sc = g1[t] * rsqrtf(var + EPSBN);
    bn1s[t] = sc;
    bn1s[64 + t] = bt1[t] - m * sc;
  }
}

// ---------------- fused transformer (rank-64 collapsed): 8192 blocks x 64 ----------------
__global__ __launch_bounds__(64) void transformer_fused(
    float* __restrict__ x1, const float* __restrict__ bn1s,
    const float* __restrict__ G, const float* __restrict__ u, const float* __restrict__ w,
    const float* __restrict__ cc, const float* __restrict__ ZT, const float* __restrict__ tb) {
  __shared__ float pre[16][65];
  __shared__ float ts[16][65];
  __shared__ float ys[16][65];
  __shared__ float ss[16][17];
  __shared__ float spu[16], spw[16];
  const int c = threadIdx.x;
  const size_t base = (size_t)blockIdx.x * 1024;
  const float sc = bn1s[c], sh = bn1s[64 + c];
  float pc[16];
#pragma unroll
  for (int k = 0; k < 16; ++k) {
    float v = x1[base + k * 64 + c];
    float p = fmaxf(0.f, v * sc + sh);
    pc[k] = p; pre[k][c] = p;
  }
  __syncthreads();
  float tcol[16], ycol[16];
#pragma unroll
  for (int k = 0; k < 16; ++k) { tcol[k] = 0.f; ycol[k] = 0.f; }
  for (int i = 0; i < 64; ++i) {
    float g = G[i * 64 + c];
    float z = ZT[i * 64 + c];
#pragma unroll
    for (int k = 0; k < 16; ++k) {
      float p = pre[k][i];
      tcol[k] = fmaf(p, g, tcol[k]);
      ycol[k] = fmaf(p, z, ycol[k]);
    }
  }
#pragma unroll
  for (int k = 0; k < 16; ++k) { ts[k][c] = tcol[k]; ys[k][c] = ycol[k]; }
  if (c < 16) {
    float s = 0.f;
    for (int i = 0; i < 64; ++i) s = fmaf(pre[c][i], u[i], s);
    spu[c] = s;
  } else if (c < 32) {
    int m = c - 16; float s = 0.f;
    for (int i = 0; i < 64; ++i) s = fmaf(pre[m][i], w[i], s);
    spw[m] = s;
  }
  __syncthreads();
  {
    const float cval = cc[0];
    const int m = c & 15, nb = c >> 4;
#pragma unroll
    for (int ng = 0; ng < 4; ++ng) {
      int n = ng * 4 + nb;
      float s = 0.f;
      for (int i = 0; i < 64; ++i) s = fmaf(ts[n][i], pre[m][i], s);
      ss[n][m] = s + spu[n] + spw[m] + cval;
    }
  }
  __syncthreads();
  if (c < 16) {
    float mx = -3.4e38f;
#pragma unroll
    for (int m = 0; m < 16; ++m) mx = fmaxf(mx, ss[c][m]);
    float e[16], sum = 0.f;
#pragma unroll
    for (int m = 0; m < 16; ++m) { e[m] = expf(ss[c][m] - mx); sum += e[m]; }
    float r = 1.0f / sum;
#pragma unroll
    for (int m = 0; m < 16; ++m) ss[c][m] = e[m] * r;
  }
  __syncthreads();
  const float tbc = tb[c];
  float o[16];
#pragma unroll
  for (int k = 0; k < 16; ++k) o[k] = 0.f;
#pragma unroll
  for (int m = 0; m < 16; ++m) {
    float yv = ys[m][c];
#pragma unroll
    for (int k = 0; k < 16; ++k) o[k] = fmaf(ss[k][m], yv, o[k]);
  }
#pragma unroll
  for (int k = 0; k < 16; ++k) x1[base + k * 64 + c] = o[k] + tbc + pc[k];
}

// ---------------- BN2 stats (computes mlp2 on the fly): 1024 blocks x 256 ----------------
__global__ __launch_bounds__(256) void bn2_stats_kernel(const float* __restrict__ x2,
                                                        const float* __restrict__ w2,
                                                        const float* __restrict__ b2,
                                                        float* __restrict__ bnp2) {
  __shared__ float sx2[128 * 64];
  __shared__ float ps[2][128], pq[2][128];
  const int t = threadIdx.x;
  const float4* s4 = reinterpret_cast<const float4*>(x2 + (size_t)blockIdx.x * 128 * 64);
  float4* d4 = reinterpret_cast<float4*>(sx2);
  for (int i = 0; i < 8; ++i) d4[i * 256 + t] = s4[i * 256 + t];
  __syncthreads();
  const int c = t & 127, h = t >> 7;
  float4 wreg[16];
  const float4* w4 = reinterpret_cast<const float4*>(w2 + c * 64);
#pragma unroll
  for (int i = 0; i < 16; ++i) wreg[i] = w4[i];
  const float bb = b2[c];
  float s = 0.f, q = 0.f;
  for (int p = 0; p < 64; ++p) {
    const float4* xr = reinterpret_cast<const float4*>(&sx2[(h * 64 + p) * 64]);
    float acc = bb;
#pragma unroll
    for (int i = 0; i < 16; ++i) {
      float4 xv = xr[i];
      acc += xv.x * wreg[i].x + xv.y * wreg[i].y + xv.z * wreg[i].z + xv.w * wreg[i].w;
    }
    s += acc; q = fmaf(acc, acc, q);
  }
  ps[h][c] = s; pq[h][c] = q;
  __syncthreads();
  if (t < 128) {
    bnp2[blockIdx.x * 256 + t]       = ps[0][t] + ps[1][t];
    bnp2[blockIdx.x * 256 + 128 + t] = pq[0][t] + pq[1][t];
  }
}

// parallelized: 1 block x 512 (c = t&127, g = t>>7 handles 256 partials)
__global__ __launch_bounds__(512) void bn2_final_kernel(const float* __restrict__ bnp2,
                                                        const float* __restrict__ g2,
                                                        const float* __restrict__ bt2,
                                                        float* __restrict__ bn2s) {
  __shared__ float rs[4][128], rq[4][128];
  const int t = threadIdx.x, c = t & 127, g = t >> 7;
  float S = 0.f, Q = 0.f;
  for (int i = g * 256; i < g * 256 + 256; ++i) {
    S += bnp2[i * 256 + c];
    Q += bnp2[i * 256 + 128 + c];
  }
  rs[g][c] = S; rq[g][c] = Q;
  __syncthreads();
  if (t < 128) {
    float Sa = rs[0][t] + rs[1][t] + rs[2][t] + rs[3][t];
    float Qa = rq[0][t] + rq[1][t] + rq[2][t] + rq[3][t];
    float m = Sa * (1.0f / 131072.0f);
    float var = Qa * (1.0f / 131072.0f) - m * m;
    float sc = g2[t] * rsqrtf(var + EPSBN);
    bn2s[t] = sc;
    bn2s[128 + t] = bt2[t] - m * sc;
  }
}

// ---------------- final: mlp2 + BN2 + ReLU + maxpool: 8192 blocks x 128 ----------------
__global__ __launch_bounds__(128) void final_kernel(const float* __restrict__ x2,
                                                    const float* __restrict__ w2,
                                                    const float* __restrict__ b2,
                                                    const float* __restrict__ bn2s,
                                                    float* __restrict__ out) {
  __shared__ float sx2[16 * 64];
  const int t = threadIdx.x;
  const float4* s4 = reinterpret_cast<const float4*>(x2 + (size_t)blockIdx.x * 1024);
  float4* d4 = reinterpret_cast<float4*>(sx2);
  for (int i = 0; i < 2; ++i) d4[i * 128 + t] = s4[i * 128 + t];
  __syncthreads();
  const int c = t;
  float4 wreg[16];
  const float4* w4 = reinterpret_cast<const float4*>(w2 + c * 64);
#pragma unroll
  for (int i = 0; i < 16; ++i) wreg[i] = w4[i];
  const float bb = b2[c], sc = bn2s[c], sh = bn2s[128 + c];
  float mx = -3.4e38f;
  for (int k = 0; k < 16; ++k) {
    const float4* xr = reinterpret_cast<const float4*>(&sx2[k * 64]);
    float acc = bb;
#pragma unroll
    for (int i = 0; i < 16; ++i) {
      float4 xv = xr[i];
      acc += xv.x * wreg[i].x + xv.y * wreg[i].y + xv.z * wreg[i].z + xv.w * wreg[i].w;
    }
    float y = fmaxf(0.f, acc * sc + sh);
    mx = fmaxf(mx, y);
  }
  out[24576 + (size_t)blockIdx.x * 128 + c] = mx;
}

// ---------------- launch ----------------
extern "C" void kernel_launch(void* const* d_in, const int* in_sizes, int n_in,
                              void* d_out, int out_size, void* d_ws, size_t ws_size,
                              hipStream_t stream) {
  const float* xyz  = (const float*)d_in[0];
  const float* feat = (const float*)d_in[1];
  const float* w1   = (const float*)d_in[2];
  const float* b1   = (const float*)d_in[3];
  const float* g1   = (const float*)d_in[4];
  const float* bt1  = (const float*)d_in[5];
  const float* fc1w = (const float*)d_in[6];
  const float* fc1b = (const float*)d_in[7];
  const float* wq   = (const float*)d_in[8];
  const float* wk   = (const float*)d_in[9];
  const float* wv   = (const float*)d_in[10];
  const float* fc2w = (const float*)d_in[11];
  const float* fc2b = (const float*)d_in[12];
  const float* w2   = (const float*)d_in[13];
  const float* b2   = (const float*)d_in[14];
  const float* g2   = (const float*)d_in[15];
  const float* bt2  = (const float*)d_in[16];
  float* out = (float*)d_out;
  char* ws = (char*)d_ws;

  int*    knn_idx = (int*)(ws + WS_KNN_IDX);
  float*  x1      = (float*)(ws + WS_X1);
  float*  bnp1    = (float*)(ws + WS_BNP1);
  float*  bn1s    = (float*)(ws + WS_BN1S);
  float*  bnp2    = (float*)(ws + WS_BNP2);
  float*  bn2s    = (float*)(ws + WS_BN2S);
  float*  Abuf    = (float*)(ws + WS_A);
  float*  Bbuf    = (float*)(ws + WS_B);
  float*  qb      = (float*)(ws + WS_QB);
  float*  kb      = (float*)(ws + WS_KB);
  float*  Wc      = (float*)(ws + WS_WC);
  float*  G       = (float*)(ws + WS_G);
  float*  ZT      = (float*)(ws + WS_ZT);
  float*  u       = (float*)(ws + WS_U);
  float*  w       = (float*)(ws + WS_W);
  float*  tb      = (float*)(ws + WS_TB);
  float*  cc      = (float*)(ws + WS_CC);
  float4* pts4    = (float4*)(ws + WS_PTS4);

  prep1_kernel<<<512, 256, 0, stream>>>(wq, wk, fc1w, fc1b, fc2w, wv, xyz,
                                        Abuf, Bbuf, qb, kb, Wc, pts4);
  prep2_kernel<<<34, 256, 0, stream>>>(Abuf, Bbuf, qb, kb, Wc, fc1w, fc1b, fc2b,
                                       G, u, w, cc, ZT, tb);

  fps_kernel<<<8, 256, 0, stream>>>(pts4, out);
  knn_kernel<<<2048, 256, 0, stream>>>(pts4, out, knn_idx);
  mlp1_kernel<<<512, 256, 0, stream>>>(feat, knn_idx, w1, b1, x1);
  bn1_stats_kernel<<<512, 256, 0, stream>>>(x1, bnp1);
  bn1_final_kernel<<<1, 256, 0, stream>>>(bnp1, g1, bt1, bn1s);
  transformer_fused<<<8192, 64, 0, stream>>>(x1, bn1s, G, u, w, cc, ZT, tb);
  bn2_stats_kernel<<<1024, 256, 0, stream>>>(x1, w2, b2, bnp2);
  bn2_final_kernel<<<1, 512, 0, stream>>>(bnp2, g2, bt2, bn2s);
  final_kernel<<<8192, 128, 0, stream>>>(x1, w2, b2, bn2s, out);
}